// Round 5
// baseline (321.373 us; speedup 1.0000x reference)
//
#include <hip/hip_runtime.h>
#include <math.h>

// Shapes (fixed by the reference)
#define B_    512
#define T_    512
#define DEC_  128
#define EMB_  512
#define VOC_  30001
#define VEXT_ 30051   // VOC_ + 50 OOV

typedef float f32x4 __attribute__((ext_vector_type(4)));
typedef short s16x4 __attribute__((ext_vector_type(4)));

#define L2E 1.4426950408889634f

__device__ __forceinline__ float sigmoid_f(float x) {
  float xc = fminf(fmaxf(x, -30.f), 30.f);
  float t = exp2f(xc * L2E);
  return t / (1.f + t);
}
__device__ __forceinline__ float tanh_f(float x) {
  float xc = fminf(fmaxf(x, -15.f), 15.f);
  float t = exp2f(xc * (2.f * L2E));
  return (t - 1.f) / (t + 1.f);
}
// f32 -> bf16 (RNE)
__device__ __forceinline__ short f2bf(float f) {
  unsigned u = __builtin_bit_cast(unsigned, f);
  u += 0x7FFFu + ((u >> 16) & 1u);
  return (short)(u >> 16);
}

// ---------------------------------------------------------------------------
// K0: convert Wh_w (128x128 f32) to bf16 MFMA B-fragments, fragment-linear:
// bw[((nf*8+kf)*64 + lane)*4 + e] = Whw[nf*16 + (lane&15)][kf*16 + (lane>>4)*4 + e]
// ---------------------------------------------------------------------------
__global__ __launch_bounds__(256) void k0_prep(
    const float* __restrict__ Whw, unsigned short* __restrict__ bw) {
  const int t = threadIdx.x;
#pragma unroll
  for (int i = 0; i < 16; ++i) {
    int p = t + 256 * i;          // (frag, lane) pair
    int f = p >> 6, l = p & 63;
    int nf = f >> 3, kf = f & 7;
    int rowN = nf * 16 + (l & 15);
    int colK = kf * 16 + (l >> 4) * 4;
    f32x4 w = *(const f32x4*)(Whw + rowN * 128 + colK);
    s16x4 bb; bb[0] = f2bf(w[0]); bb[1] = f2bf(w[1]); bb[2] = f2bf(w[2]); bb[3] = f2bf(w[3]);
    *(s16x4*)&bw[p * 4] = bb;
  }
}

// ---------------------------------------------------------------------------
// K0b: convert V2_w (30001x384 f32) to bf16 MFMA B-fragments, frag-linear:
// global frag index fb = (nb*4+nf)*24 + kf (vg = nb*4+nf = 0..1875)
// v2bf[(fb*64 + lane)*4 + e] = V2w[vg*16 + (lane&15)][kf*16 + (lane>>4)*4 + e]
// Writes perfectly coalesced; reads line-grouped across neighboring threads.
// grid = 11256 x 256 (2,881,536 (frag,lane) pairs).
// ---------------------------------------------------------------------------
__global__ __launch_bounds__(256) void k0b_prepv2(
    const float* __restrict__ V2w, unsigned short* __restrict__ v2bf) {
  int p = blockIdx.x * 256 + threadIdx.x;
  int f = p >> 6, lane = p & 63;
  int lm = lane & 15, lg = lane >> 4;
  int vg = f / 24, kf = f - vg * 24;
  int v = vg * 16 + lm;
  f32x4 w = {0.f, 0.f, 0.f, 0.f};
  if (v < VOC_) w = *(const f32x4*)(V2w + (size_t)v * 384 + kf * 16 + lg * 4);
  s16x4 bb; bb[0] = f2bf(w[0]); bb[1] = f2bf(w[1]); bb[2] = f2bf(w[2]); bb[3] = f2bf(w[3]);
  *(s16x4*)&v2bf[(size_t)p * 4] = bb;
}

// ---------------------------------------------------------------------------
// K1: x1[b,f] = sum_k [emb[x[b]] | ctx_prev][b,k] * W1_w[f,k] + W1_b[f]
// ---------------------------------------------------------------------------
__global__ __launch_bounds__(256) void k1_x1(
    const float* __restrict__ emb, const int* __restrict__ x,
    const float* __restrict__ ctxp, const float* __restrict__ W1w,
    const float* __restrict__ W1b, float* __restrict__ x1) {
  __shared__ float As[32][33];
  __shared__ float Ws[32][33];
  const int tid = threadIdx.x;
  const int f0 = blockIdx.x * 32, b0 = blockIdx.y * 32;
  const int row = tid >> 3, seg = tid & 7;
  const int tx = tid & 15, ty = tid >> 4;
  float a00 = 0.f, a01 = 0.f, a10 = 0.f, a11 = 0.f;
  for (int k0 = 0; k0 < 640; k0 += 32) {
    int k = k0 + seg * 4;
    f32x4 av;
    if (k < 512) {
      int xb = x[b0 + row];
      av = *(const f32x4*)(emb + xb * 512 + k);
    } else {
      av = *(const f32x4*)(ctxp + (b0 + row) * 128 + (k - 512));
    }
    As[row][seg * 4 + 0] = av[0]; As[row][seg * 4 + 1] = av[1];
    As[row][seg * 4 + 2] = av[2]; As[row][seg * 4 + 3] = av[3];
    f32x4 wv = *(const f32x4*)(W1w + (f0 + row) * 640 + k);
    Ws[row][seg * 4 + 0] = wv[0]; Ws[row][seg * 4 + 1] = wv[1];
    Ws[row][seg * 4 + 2] = wv[2]; Ws[row][seg * 4 + 3] = wv[3];
    __syncthreads();
#pragma unroll
    for (int kk = 0; kk < 32; ++kk) {
      float v0 = As[ty * 2][kk], v1 = As[ty * 2 + 1][kk];
      float w0 = Ws[tx * 2][kk], w1 = Ws[tx * 2 + 1][kk];
      a00 += v0 * w0; a01 += v0 * w1; a10 += v1 * w0; a11 += v1 * w1;
    }
    __syncthreads();
  }
  int fo = f0 + tx * 2, bo = b0 + ty * 2;
  x1[bo * 512 + fo]           = a00 + W1b[fo];
  x1[bo * 512 + fo + 1]       = a01 + W1b[fo + 1];
  x1[(bo + 1) * 512 + fo]     = a10 + W1b[fo];
  x1[(bo + 1) * 512 + fo + 1] = a11 + W1b[fo + 1];
}

// ---------------------------------------------------------------------------
// K2: gates[b,j] = sum [x1 | h_prev][b,k] * [W_ih | W_hh][j,k] + b_ih + b_hh
// ---------------------------------------------------------------------------
__global__ __launch_bounds__(256) void k2_gates(
    const float* __restrict__ x1, const float* __restrict__ hprev,
    const float* __restrict__ Wih, const float* __restrict__ Whh,
    const float* __restrict__ bih, const float* __restrict__ bhh,
    float* __restrict__ gates) {
  __shared__ float As[32][33];
  __shared__ float Ws[32][33];
  const int tid = threadIdx.x;
  const int f0 = blockIdx.x * 32, b0 = blockIdx.y * 32;
  const int row = tid >> 3, seg = tid & 7;
  const int tx = tid & 15, ty = tid >> 4;
  float a00 = 0.f, a01 = 0.f, a10 = 0.f, a11 = 0.f;
  for (int k0 = 0; k0 < 640; k0 += 32) {
    int k = k0 + seg * 4;
    f32x4 av, wv;
    if (k < 512) {
      av = *(const f32x4*)(x1 + (b0 + row) * 512 + k);
      wv = *(const f32x4*)(Wih + (f0 + row) * 512 + k);
    } else {
      av = *(const f32x4*)(hprev + (b0 + row) * 128 + (k - 512));
      wv = *(const f32x4*)(Whh + (f0 + row) * 128 + (k - 512));
    }
    As[row][seg * 4 + 0] = av[0]; As[row][seg * 4 + 1] = av[1];
    As[row][seg * 4 + 2] = av[2]; As[row][seg * 4 + 3] = av[3];
    Ws[row][seg * 4 + 0] = wv[0]; Ws[row][seg * 4 + 1] = wv[1];
    Ws[row][seg * 4 + 2] = wv[2]; Ws[row][seg * 4 + 3] = wv[3];
    __syncthreads();
#pragma unroll
    for (int kk = 0; kk < 32; ++kk) {
      float v0 = As[ty * 2][kk], v1 = As[ty * 2 + 1][kk];
      float w0 = Ws[tx * 2][kk], w1 = Ws[tx * 2 + 1][kk];
      a00 += v0 * w0; a01 += v0 * w1; a10 += v1 * w0; a11 += v1 * w1;
    }
    __syncthreads();
  }
  int fo = f0 + tx * 2, bo = b0 + ty * 2;
  gates[bo * 512 + fo]           = a00 + bih[fo] + bhh[fo];
  gates[bo * 512 + fo + 1]       = a01 + bih[fo + 1] + bhh[fo + 1];
  gates[(bo + 1) * 512 + fo]     = a10 + bih[fo] + bhh[fo];
  gates[(bo + 1) * 512 + fo + 1] = a11 + bih[fo + 1] + bhh[fo + 1];
}

// ---------------------------------------------------------------------------
// K3: LSTM cell + dec_f = s_t @ Ws_w^T + Ws_b.  One block per b, 128 threads.
// ---------------------------------------------------------------------------
__global__ __launch_bounds__(128) void k3_lstm(
    const float* __restrict__ gates, const float* __restrict__ cprev,
    const float* __restrict__ Wsw, const float* __restrict__ Wsb,
    float* __restrict__ out_h, float* __restrict__ out_c,
    float* __restrict__ decf) {
  __shared__ float st[256];
  int b = blockIdx.x, d = threadIdx.x;
  const float* g = gates + b * 512;
  float iv = sigmoid_f(g[d]);
  float fv = sigmoid_f(g[128 + d]);
  float gv = tanh_f(g[256 + d]);
  float ov = sigmoid_f(g[384 + d]);
  float c = fv * cprev[b * 128 + d] + iv * gv;
  float h = ov * tanh_f(c);
  out_h[b * 128 + d] = h;
  out_c[b * 128 + d] = c;
  st[d] = h; st[128 + d] = c;
  __syncthreads();
  float acc = Wsb[d];
  const float* wr = Wsw + d * 256;
#pragma unroll 4
  for (int k = 0; k < 256; ++k) acc += st[k] * wr[k];
  decf[b * 128 + d] = acc;
}

// ---------------------------------------------------------------------------
// K4 v2: e_t[b,t] = V_w . tanh(h_i@Wh^T + dec_f[b] + cov[b,t]*Wc)
// grid = B*4 = 2048 blocks (4 waves each), wave owns 32 t x all 128 d.
// ---------------------------------------------------------------------------
__global__ __launch_bounds__(256, 4) void k4_et(
    const float* __restrict__ h_i, const unsigned short* __restrict__ bw,
    const float* __restrict__ decf, const float* __restrict__ cov,
    const float* __restrict__ Wcw, const float* __restrict__ Vw,
    float* __restrict__ e_t) {
  const int b = blockIdx.x >> 2;
  const int q = blockIdx.x & 3;
  const int wv = threadIdx.x >> 6;
  const int lane = threadIdx.x & 63;
  const int lm = lane & 15, lg = lane >> 4;
  const int t0 = q * 128 + wv * 32;

  s16x4 afr[2][8];
#pragma unroll
  for (int mf = 0; mf < 2; ++mf) {
#pragma unroll
    for (int kf = 0; kf < 8; ++kf) {
      const float* p = h_i + (size_t)(b * 512 + t0 + mf * 16 + lm) * 128 + kf * 16 + lg * 4;
      f32x4 v = *(const f32x4*)p;
      s16x4 a; a[0] = f2bf(v[0]); a[1] = f2bf(v[1]); a[2] = f2bf(v[2]); a[3] = f2bf(v[3]);
      afr[mf][kf] = a;
    }
  }
  float dec_v[8], vw_v[8], wc_v[8];
#pragma unroll
  for (int nf = 0; nf < 8; ++nf) {
    dec_v[nf] = decf[b * 128 + nf * 16 + lm];
    vw_v[nf]  = Vw[nf * 16 + lm];
    wc_v[nf]  = Wcw[nf * 16 + lm];
  }
  float cov_v[8];
#pragma unroll
  for (int mf = 0; mf < 2; ++mf)
#pragma unroll
    for (int r = 0; r < 4; ++r)
      cov_v[mf * 4 + r] = cov[b * 512 + t0 + mf * 16 + lg * 4 + r];

  float e_acc[8];
#pragma unroll
  for (int i = 0; i < 8; ++i) e_acc[i] = 0.f;

  const f32x4 zf4 = {0.f, 0.f, 0.f, 0.f};
#pragma unroll
  for (int nf = 0; nf < 8; ++nf) {
    s16x4 bfr[8];
#pragma unroll
    for (int kf = 0; kf < 8; ++kf)
      bfr[kf] = *(const s16x4*)&bw[(((nf * 8 + kf) * 64) + lane) * 4];
    f32x4 acc0 = zf4, acc1 = zf4;
#pragma unroll
    for (int kf = 0; kf < 8; ++kf) {
      acc0 = __builtin_amdgcn_mfma_f32_16x16x16bf16_1k(afr[0][kf], bfr[kf], acc0, 0, 0, 0);
      acc1 = __builtin_amdgcn_mfma_f32_16x16x16bf16_1k(afr[1][kf], bfr[kf], acc1, 0, 0, 0);
    }
#pragma unroll
    for (int r = 0; r < 4; ++r) {
      float v0 = acc0[r] + dec_v[nf] + cov_v[r] * wc_v[nf];
      e_acc[r] += vw_v[nf] * tanh_f(v0);
      float v1 = acc1[r] + dec_v[nf] + cov_v[4 + r] * wc_v[nf];
      e_acc[4 + r] += vw_v[nf] * tanh_f(v1);
    }
  }
#pragma unroll
  for (int i = 0; i < 8; ++i) {
    float v = e_acc[i];
    v += __shfl_xor(v, 1); v += __shfl_xor(v, 2);
    v += __shfl_xor(v, 4); v += __shfl_xor(v, 8);
    e_acc[i] = v;
  }
  if (lm == 0) {
#pragma unroll
    for (int mf = 0; mf < 2; ++mf)
#pragma unroll
      for (int r = 0; r < 4; ++r)
        e_t[b * 512 + t0 + mf * 16 + lg * 4 + r] = e_acc[mf * 4 + r];
  }
}

// ---------------------------------------------------------------------------
// K5: softmax over t, coverage_new, ctx = sum_t a_t * h_i. One block per b.
// ---------------------------------------------------------------------------
__global__ __launch_bounds__(256) void k5_softmax_ctx(
    const float* __restrict__ e_t, const float* __restrict__ cov,
    const float* __restrict__ h_i, float* __restrict__ a_t,
    float* __restrict__ cov_out, float* __restrict__ ctx_out) {
  __shared__ float sm[512];
  __shared__ float red[1024];
  __shared__ float wred[8];
  int b = blockIdx.x, tid = threadIdx.x;
  float e0 = e_t[b * 512 + tid], e1 = e_t[b * 512 + 256 + tid];
  float m = fmaxf(e0, e1);
  for (int off = 32; off; off >>= 1) m = fmaxf(m, __shfl_xor(m, off));
  if ((tid & 63) == 0) wred[tid >> 6] = m;
  __syncthreads();
  m = fmaxf(fmaxf(wred[0], wred[1]), fmaxf(wred[2], wred[3]));
  float x0 = exp2f((e0 - m) * L2E);
  float x1v = exp2f((e1 - m) * L2E);
  float s = x0 + x1v;
  for (int off = 32; off; off >>= 1) s += __shfl_xor(s, off);
  if ((tid & 63) == 0) wred[4 + (tid >> 6)] = s;
  __syncthreads();
  s = wred[4] + wred[5] + wred[6] + wred[7];
  float inv = 1.f / s;
  float a0 = x0 * inv, a1 = x1v * inv;
  a_t[b * 512 + tid] = a0;
  a_t[b * 512 + 256 + tid] = a1;
  cov_out[b * 512 + tid] = cov[b * 512 + tid] + a0;
  cov_out[b * 512 + 256 + tid] = cov[b * 512 + 256 + tid] + a1;
  sm[tid] = a0; sm[256 + tid] = a1;
  __syncthreads();
  int j = tid & 31, tg = tid >> 5;
  const float* hb = h_i + (size_t)b * 512 * 128 + j * 4;
  f32x4 acc = {0.f, 0.f, 0.f, 0.f};
#pragma unroll 8
  for (int t = tg; t < 512; t += 8) {
    float a = sm[t];
    f32x4 hv = *(const f32x4*)(hb + (size_t)t * 128);
    acc += hv * a;
  }
  *(f32x4*)&red[tid * 4] = acc;
  __syncthreads();
  if (tid < 128) {
    float sacc = 0.f;
#pragma unroll
    for (int g = 0; g < 8; ++g) sacc += red[g * 128 + tid];
    ctx_out[b * 128 + tid] = sacc;
  }
}

// ---------------------------------------------------------------------------
// K6: pv1(bf16) = [h|ctx]@V1^T + V1_b ; p_gen ; attn_dist = (1-p_gen)*a_t
// ---------------------------------------------------------------------------
__global__ __launch_bounds__(256) void k6_pv1_pgen(
    const float* __restrict__ out_h, const float* __restrict__ out_c,
    const float* __restrict__ ctx, const float* __restrict__ emb,
    const int* __restrict__ x, const float* __restrict__ V1w,
    const float* __restrict__ V1b, const float* __restrict__ W2w,
    const float* __restrict__ W2b, const float* __restrict__ a_t,
    unsigned short* __restrict__ pv1bf, float* __restrict__ pgen,
    float* __restrict__ attn_out) {
  __shared__ float cat[896];  // [ctx(128) | h(128) | c(128) | xe(512)]
  __shared__ float wr_[4];
  int b = blockIdx.x, tid = threadIdx.x;
  if (tid < 128) {
    cat[tid] = ctx[b * 128 + tid];
    cat[128 + tid] = out_h[b * 128 + tid];
  } else {
    int q = tid - 128;
    cat[256 + q] = out_c[b * 128 + q];
  }
  int xb = x[b];
  for (int k = tid; k < 512; k += 256) cat[384 + k] = emb[xb * 512 + k];
  __syncthreads();
  for (int f = tid; f < 384; f += 256) {
    const float* w = V1w + f * 256;
    float acc = V1b[f];
#pragma unroll 4
    for (int k = 0; k < 256; ++k) {
      float av = (k < 128) ? cat[128 + k] : cat[k - 128];
      acc += av * w[k];
    }
    pv1bf[b * 384 + f] = (unsigned short)f2bf(acc);
  }
  float p = 0.f;
  for (int k = tid; k < 896; k += 256) p += cat[k] * W2w[k];
  for (int off = 32; off; off >>= 1) p += __shfl_xor(p, off);
  if ((tid & 63) == 0) wr_[tid >> 6] = p;
  __syncthreads();
  float pg = sigmoid_f(wr_[0] + wr_[1] + wr_[2] + wr_[3] + W2b[0]);
  if (tid == 0) pgen[b] = pg;
  float om = 1.f - pg;
  attn_out[b * 512 + tid]       = om * a_t[b * 512 + tid];
  attn_out[b * 512 + 256 + tid] = om * a_t[b * 512 + 256 + tid];
}

// ---------------------------------------------------------------------------
// K7 v3 (global-fragment, k4-style): logits = pv1 @ V2_w^T + V2_b -> d_out.
// NO LDS, NO barrier: B comes pre-converted frag-linear from k0b (global,
// L2/L3-cached). grid = 3776 blocks x 256 thr (24 early-exit).
// Block q -> nb = (q>>6)*8 + (q&7), mg = (q>>3)&7, so all 8 same-panel
// blocks share q%8 -> same XCD (L2 panel reuse). Wave = 16 rows x 64 vcols.
// ---------------------------------------------------------------------------
__global__ __launch_bounds__(256, 4) void k7_vocab_gf(
    const unsigned short* __restrict__ pv1bf, const unsigned short* __restrict__ v2bf,
    const float* __restrict__ V2b, float* __restrict__ outF) {
  const int q = blockIdx.x;
  const int nb = ((q >> 6) << 3) + (q & 7);
  const int mg = (q >> 3) & 7;
  if (nb >= 469) return;
  const int v0 = nb * 64;
  const int tid = threadIdx.x;
  const int wv = tid >> 6, lane = tid & 63;
  const int lm = lane & 15, lg = lane >> 4;
  const int r0 = mg * 64 + wv * 16;

  // A fragments (pv1 is 384 KB, L2-hot)
  s16x4 afr[24];
#pragma unroll
  for (int kf = 0; kf < 24; ++kf)
    afr[kf] = *(const s16x4*)&pv1bf[(r0 + lm) * 384 + kf * 16 + lg * 4];

  const unsigned short* bnb = v2bf + (size_t)nb * 96 * 256 + lane * 4;  // 96 frags x 256 shorts
  const f32x4 zf4 = {0.f, 0.f, 0.f, 0.f};
  f32x4 acc[4] = {zf4, zf4, zf4, zf4};
#pragma unroll
  for (int kf = 0; kf < 24; ++kf) {
#pragma unroll
    for (int nf = 0; nf < 4; ++nf) {
      s16x4 bfr = *(const s16x4*)&bnb[(size_t)(nf * 24 + kf) * 256];
      acc[nf] = __builtin_amdgcn_mfma_f32_16x16x16bf16_1k(afr[kf], bfr, acc[nf], 0, 0, 0);
    }
  }

  // D[i=4*lg+r][j=lm]: row = r0 + 4*lg + r, vcol = v0 + nf*16 + lm
#pragma unroll
  for (int nf = 0; nf < 4; ++nf) {
    int vcol = v0 + nf * 16 + lm;
    if (vcol < VOC_) {
      float bias = V2b[vcol];
      int rbase = r0 + lg * 4;
#pragma unroll
      for (int r = 0; r < 4; ++r)
        outF[(size_t)(rbase + r) * VEXT_ + vcol] = acc[nf][r] + bias;
    }
  }
}

// ---------------------------------------------------------------------------
// K7 fallback (round-3 LDS version) -- used only if ws_size can't hold v2bf.
// ---------------------------------------------------------------------------
__global__ __launch_bounds__(512) void k7_vocab_lds(
    const unsigned short* __restrict__ pv1bf, const float* __restrict__ V2w,
    const float* __restrict__ V2b, float* __restrict__ outF) {
  __shared__ unsigned short Bl[64 * 392];
  const int bx = blockIdx.x;
  const int nb = bx >> 1, mh = bx & 1;
  const int v0 = nb * 64;
  const int tid = threadIdx.x;
  {
    int vl = tid >> 3, kg = tid & 7;
    int v = v0 + vl;
    bool ok = (v < VOC_);
    const float* src = V2w + (size_t)v * 384;
    const f32x4 zf4 = {0.f, 0.f, 0.f, 0.f};
#pragma unroll
    for (int u = 0; u < 12; ++u) {
      int k = u * 32 + kg * 4;
      f32x4 w = ok ? *(const f32x4*)(src + k) : zf4;
      s16x4 bb; bb[0] = f2bf(w[0]); bb[1] = f2bf(w[1]); bb[2] = f2bf(w[2]); bb[3] = f2bf(w[3]);
      *(s16x4*)&Bl[vl * 392 + k] = bb;
    }
  }
  const int wv = tid >> 6, lane = tid & 63;
  const int lm = lane & 15, lg = lane >> 4;
  const int m0 = mh * 256 + wv * 32;
  s16x4 afr[2][24];
#pragma unroll
  for (int mf = 0; mf < 2; ++mf)
#pragma unroll
    for (int kf = 0; kf < 24; ++kf)
      afr[mf][kf] = *(const s16x4*)&pv1bf[(m0 + mf * 16 + lm) * 384 + kf * 16 + lg * 4];
  __syncthreads();

  const f32x4 zf4 = {0.f, 0.f, 0.f, 0.f};
  for (int nt = 0; nt < 4; ++nt) {
    int nl = nt * 16 + lm;
    f32x4 acc0 = zf4, acc1 = zf4;
#pragma unroll
    for (int kf = 0; kf < 24; ++kf) {
      s16x4 bf_ = *(const s16x4*)&Bl[nl * 392 + kf * 16 + lg * 4];
      acc0 = __builtin_amdgcn_mfma_f32_16x16x16bf16_1k(afr[0][kf], bf_, acc0, 0, 0, 0);
      acc1 = __builtin_amdgcn_mfma_f32_16x16x16bf16_1k(afr[1][kf], bf_, acc1, 0, 0, 0);
    }
    int vcol = v0 + nl;
    if (vcol < VOC_) {
      float bias = V2b[vcol];
#pragma unroll
      for (int r = 0; r < 4; ++r) {
        outF[(size_t)(m0 + lg * 4 + r) * VEXT_ + vcol]      = acc0[r] + bias;
        outF[(size_t)(m0 + 16 + lg * 4 + r) * VEXT_ + vcol] = acc1[r] + bias;
      }
    }
  }
}

// ---------------------------------------------------------------------------
// K8: per-row softmax of logits (in d_out), scale by p_gen, zero the 50 OOV
// cols, scatter-add attn_dist with WORKGROUP-scope atomics. One block per b.
// ---------------------------------------------------------------------------
#define K8_IT 30  // ceil(VOC_/1024)

__global__ __launch_bounds__(1024) void k8_final(
    const float* __restrict__ pgen, const int* __restrict__ code_ext,
    const float* __restrict__ attn, float* __restrict__ outF) {
  __shared__ float lm_[16], ls_[16];
  const int b = blockIdx.x, tid = threadIdx.x;
  float* row = outF + (size_t)b * VEXT_;

  float lv[K8_IT];
#pragma unroll
  for (int i = 0; i < K8_IT; ++i) {
    int v = tid + i * 1024;
    lv[i] = (v < VOC_) ? row[v] : -3.4e38f;
  }
  float m = lv[0];
#pragma unroll
  for (int i = 1; i < K8_IT; ++i) m = fmaxf(m, lv[i]);
  for (int off = 32; off; off >>= 1) m = fmaxf(m, __shfl_xor(m, off));
  if ((tid & 63) == 0) lm_[tid >> 6] = m;
  __syncthreads();
  float M = lm_[0];
#pragma unroll
  for (int i = 1; i < 16; ++i) M = fmaxf(M, lm_[i]);
  float s = 0.f;
#pragma unroll
  for (int i = 0; i < K8_IT; ++i) {
    lv[i] = exp2f((lv[i] - M) * L2E);
    s += lv[i];
  }
  for (int off = 32; off; off >>= 1) s += __shfl_xor(s, off);
  if ((tid & 63) == 0) ls_[tid >> 6] = s;
  __syncthreads();
  float S = 0.f;
#pragma unroll
  for (int i = 0; i < 16; ++i) S += ls_[i];
  float pm = pgen[b] / S;
#pragma unroll
  for (int i = 0; i < K8_IT; ++i) {
    int v = tid + i * 1024;
    if (v < VOC_) row[v] = pm * lv[i];
  }
  if (tid < 50) row[VOC_ + tid] = 0.f;
  __syncthreads();  // drains vmcnt: all row stores are at the local L2
  if (tid < 512) {
    int idx = code_ext[b * 512 + tid];
    __hip_atomic_fetch_add(&row[idx], attn[b * 512 + tid],
                           __ATOMIC_RELAXED, __HIP_MEMORY_SCOPE_WORKGROUP);
  }
}

// ---------------------------------------------------------------------------
extern "C" void kernel_launch(void* const* d_in, const int* in_sizes, int n_in,
                              void* d_out, int out_size, void* d_ws, size_t ws_size,
                              hipStream_t stream) {
  (void)in_sizes; (void)n_in; (void)out_size;
  const float* h_i    = (const float*)d_in[0];
  const float* h_prev = (const float*)d_in[1];
  const float* c_prev = (const float*)d_in[2];
  const float* ctxp   = (const float*)d_in[3];
  const float* cov    = (const float*)d_in[4];
  const float* emb    = (const float*)d_in[5];
  const float* Wih    = (const float*)d_in[6];
  const float* Whh    = (const float*)d_in[7];
  const float* bih    = (const float*)d_in[8];
  const float* bhh    = (const float*)d_in[9];
  const float* W1w    = (const float*)d_in[10];
  const float* W1b    = (const float*)d_in[11];
  const float* W2w    = (const float*)d_in[12];
  const float* W2b    = (const float*)d_in[13];
  const float* V1w    = (const float*)d_in[14];
  const float* V1b    = (const float*)d_in[15];
  const float* V2w    = (const float*)d_in[16];
  const float* V2b    = (const float*)d_in[17];
  const float* Whw    = (const float*)d_in[18];
  const float* Wsw    = (const float*)d_in[19];
  const float* Wsb    = (const float*)d_in[20];
  const float* Wcw    = (const float*)d_in[21];
  const float* Vw     = (const float*)d_in[22];
  const int*   x      = (const int*)d_in[23];
  const int*   code   = (const int*)d_in[24];

  float* ws    = (float*)d_ws;
  float* x1    = ws;                 // 262144
  float* gates = ws + 262144;        // 262144
  float* decf  = ws + 524288;        // 65536
  float* e_t   = ws + 589824;        // 262144
  float* a_t   = ws + 851968;        // 262144
  unsigned short* pv1bf = (unsigned short*)(ws + 1114112);  // 196608 shorts
  float* pgen  = ws + 1212416;       // 512
  // bw (bf16 Wh_w fragments) aliases the a_t region: bw lives k0..k4; a_t is
  // first written in k5. No overlap in time.
  unsigned short* bw = (unsigned short*)(ws + 851968);
  // v2bf: bf16 V2_w fragments, 11,526,144 shorts (= 5,763,072 floats)
  unsigned short* v2bf = (unsigned short*)(ws + 1212928);
  const size_t WS_NEEDED = (size_t)(1212928 + 5763072) * 4;
  const bool use_gf = (ws_size >= WS_NEEDED);

  float* outF  = (float*)d_out;                    // final_dist 512 x 30051
  float* attn  = outF + (size_t)512 * VEXT_;       // 262144
  float* o_h   = attn + 262144;                    // 65536
  float* o_c   = o_h + 65536;                      // 65536
  float* o_cov = o_c + 65536;                      // 262144
  float* o_ctx = o_cov + 262144;                   // 65536

  k0_prep<<<1, 256, 0, stream>>>(Whw, bw);
  if (use_gf) k0b_prepv2<<<11256, 256, 0, stream>>>(V2w, v2bf);
  k1_x1<<<dim3(16, 16), 256, 0, stream>>>(emb, x, ctxp, W1w, W1b, x1);
  k2_gates<<<dim3(16, 16), 256, 0, stream>>>(x1, h_prev, Wih, Whh, bih, bhh, gates);
  k3_lstm<<<512, 128, 0, stream>>>(gates, c_prev, Wsw, Wsb, o_h, o_c, decf);
  k4_et<<<2048, 256, 0, stream>>>(h_i, bw, decf, cov, Wcw, Vw, e_t);
  k5_softmax_ctx<<<512, 256, 0, stream>>>(e_t, cov, h_i, a_t, o_cov, o_ctx);
  k6_pv1_pgen<<<512, 256, 0, stream>>>(o_h, o_c, o_ctx, emb, x, V1w, V1b, W2w, W2b,
                                       a_t, pv1bf, pgen, attn);
  if (use_gf)
    k7_vocab_gf<<<3776, 256, 0, stream>>>(pv1bf, v2bf, V2b, outF);
  else
    k7_vocab_lds<<<938, 512, 0, stream>>>(pv1bf, V2w, V2b, outF);
  k8_final<<<512, 1024, 0, stream>>>(pgen, code, attn, outF);
}

// Round 6
// 301.352 us; speedup vs baseline: 1.0664x; 1.0664x over previous
//
#include <hip/hip_runtime.h>
#include <math.h>

// Shapes (fixed by the reference)
#define B_    512
#define T_    512
#define DEC_  128
#define EMB_  512
#define VOC_  30001
#define VEXT_ 30051   // VOC_ + 50 OOV

typedef float f32x4 __attribute__((ext_vector_type(4)));
typedef short s16x4 __attribute__((ext_vector_type(4)));
typedef short s16x8 __attribute__((ext_vector_type(8)));

#define L2E 1.4426950408889634f

__device__ __forceinline__ float sigmoid_f(float x) {
  float xc = fminf(fmaxf(x, -30.f), 30.f);
  float t = exp2f(xc * L2E);
  return t / (1.f + t);
}
__device__ __forceinline__ float tanh_f(float x) {
  float xc = fminf(fmaxf(x, -15.f), 15.f);
  float t = exp2f(xc * (2.f * L2E));
  return (t - 1.f) / (t + 1.f);
}
// f32 -> bf16 (RNE)
__device__ __forceinline__ short f2bf(float f) {
  unsigned u = __builtin_bit_cast(unsigned, f);
  u += 0x7FFFu + ((u >> 16) & 1u);
  return (short)(u >> 16);
}

// ---------------------------------------------------------------------------
// K0: convert Wh_w (128x128 f32) to bf16 MFMA B-fragments, fragment-linear:
// bw[((nf*8+kf)*64 + lane)*4 + e] = Whw[nf*16 + (lane&15)][kf*16 + (lane>>4)*4 + e]
// ---------------------------------------------------------------------------
__global__ __launch_bounds__(256) void k0_prep(
    const float* __restrict__ Whw, unsigned short* __restrict__ bw) {
  const int t = threadIdx.x;
#pragma unroll
  for (int i = 0; i < 16; ++i) {
    int p = t + 256 * i;          // (frag, lane) pair
    int f = p >> 6, l = p & 63;
    int nf = f >> 3, kf = f & 7;
    int rowN = nf * 16 + (l & 15);
    int colK = kf * 16 + (l >> 4) * 4;
    f32x4 w = *(const f32x4*)(Whw + rowN * 128 + colK);
    s16x4 bb; bb[0] = f2bf(w[0]); bb[1] = f2bf(w[1]); bb[2] = f2bf(w[2]); bb[3] = f2bf(w[3]);
    *(s16x4*)&bw[p * 4] = bb;
  }
}

// ---------------------------------------------------------------------------
// K1: x1[b,f] = sum_k [emb[x[b]] | ctx_prev][b,k] * W1_w[f,k] + W1_b[f]
// ---------------------------------------------------------------------------
__global__ __launch_bounds__(256) void k1_x1(
    const float* __restrict__ emb, const int* __restrict__ x,
    const float* __restrict__ ctxp, const float* __restrict__ W1w,
    const float* __restrict__ W1b, float* __restrict__ x1) {
  __shared__ float As[32][33];
  __shared__ float Ws[32][33];
  const int tid = threadIdx.x;
  const int f0 = blockIdx.x * 32, b0 = blockIdx.y * 32;
  const int row = tid >> 3, seg = tid & 7;
  const int tx = tid & 15, ty = tid >> 4;
  float a00 = 0.f, a01 = 0.f, a10 = 0.f, a11 = 0.f;
  for (int k0 = 0; k0 < 640; k0 += 32) {
    int k = k0 + seg * 4;
    f32x4 av;
    if (k < 512) {
      int xb = x[b0 + row];
      av = *(const f32x4*)(emb + xb * 512 + k);
    } else {
      av = *(const f32x4*)(ctxp + (b0 + row) * 128 + (k - 512));
    }
    As[row][seg * 4 + 0] = av[0]; As[row][seg * 4 + 1] = av[1];
    As[row][seg * 4 + 2] = av[2]; As[row][seg * 4 + 3] = av[3];
    f32x4 wv = *(const f32x4*)(W1w + (f0 + row) * 640 + k);
    Ws[row][seg * 4 + 0] = wv[0]; Ws[row][seg * 4 + 1] = wv[1];
    Ws[row][seg * 4 + 2] = wv[2]; Ws[row][seg * 4 + 3] = wv[3];
    __syncthreads();
#pragma unroll
    for (int kk = 0; kk < 32; ++kk) {
      float v0 = As[ty * 2][kk], v1 = As[ty * 2 + 1][kk];
      float w0 = Ws[tx * 2][kk], w1 = Ws[tx * 2 + 1][kk];
      a00 += v0 * w0; a01 += v0 * w1; a10 += v1 * w0; a11 += v1 * w1;
    }
    __syncthreads();
  }
  int fo = f0 + tx * 2, bo = b0 + ty * 2;
  x1[bo * 512 + fo]           = a00 + W1b[fo];
  x1[bo * 512 + fo + 1]       = a01 + W1b[fo + 1];
  x1[(bo + 1) * 512 + fo]     = a10 + W1b[fo];
  x1[(bo + 1) * 512 + fo + 1] = a11 + W1b[fo + 1];
}

// ---------------------------------------------------------------------------
// K2: gates[b,j] = sum [x1 | h_prev][b,k] * [W_ih | W_hh][j,k] + b_ih + b_hh
// ---------------------------------------------------------------------------
__global__ __launch_bounds__(256) void k2_gates(
    const float* __restrict__ x1, const float* __restrict__ hprev,
    const float* __restrict__ Wih, const float* __restrict__ Whh,
    const float* __restrict__ bih, const float* __restrict__ bhh,
    float* __restrict__ gates) {
  __shared__ float As[32][33];
  __shared__ float Ws[32][33];
  const int tid = threadIdx.x;
  const int f0 = blockIdx.x * 32, b0 = blockIdx.y * 32;
  const int row = tid >> 3, seg = tid & 7;
  const int tx = tid & 15, ty = tid >> 4;
  float a00 = 0.f, a01 = 0.f, a10 = 0.f, a11 = 0.f;
  for (int k0 = 0; k0 < 640; k0 += 32) {
    int k = k0 + seg * 4;
    f32x4 av, wv;
    if (k < 512) {
      av = *(const f32x4*)(x1 + (b0 + row) * 512 + k);
      wv = *(const f32x4*)(Wih + (f0 + row) * 512 + k);
    } else {
      av = *(const f32x4*)(hprev + (b0 + row) * 128 + (k - 512));
      wv = *(const f32x4*)(Whh + (f0 + row) * 128 + (k - 512));
    }
    As[row][seg * 4 + 0] = av[0]; As[row][seg * 4 + 1] = av[1];
    As[row][seg * 4 + 2] = av[2]; As[row][seg * 4 + 3] = av[3];
    Ws[row][seg * 4 + 0] = wv[0]; Ws[row][seg * 4 + 1] = wv[1];
    Ws[row][seg * 4 + 2] = wv[2]; Ws[row][seg * 4 + 3] = wv[3];
    __syncthreads();
#pragma unroll
    for (int kk = 0; kk < 32; ++kk) {
      float v0 = As[ty * 2][kk], v1 = As[ty * 2 + 1][kk];
      float w0 = Ws[tx * 2][kk], w1 = Ws[tx * 2 + 1][kk];
      a00 += v0 * w0; a01 += v0 * w1; a10 += v1 * w0; a11 += v1 * w1;
    }
    __syncthreads();
  }
  int fo = f0 + tx * 2, bo = b0 + ty * 2;
  gates[bo * 512 + fo]           = a00 + bih[fo] + bhh[fo];
  gates[bo * 512 + fo + 1]       = a01 + bih[fo + 1] + bhh[fo + 1];
  gates[(bo + 1) * 512 + fo]     = a10 + bih[fo] + bhh[fo];
  gates[(bo + 1) * 512 + fo + 1] = a11 + bih[fo + 1] + bhh[fo + 1];
}

// ---------------------------------------------------------------------------
// K3: LSTM cell + dec_f = s_t @ Ws_w^T + Ws_b.  One block per b, 128 threads.
// ---------------------------------------------------------------------------
__global__ __launch_bounds__(128) void k3_lstm(
    const float* __restrict__ gates, const float* __restrict__ cprev,
    const float* __restrict__ Wsw, const float* __restrict__ Wsb,
    float* __restrict__ out_h, float* __restrict__ out_c,
    float* __restrict__ decf) {
  __shared__ float st[256];
  int b = blockIdx.x, d = threadIdx.x;
  const float* g = gates + b * 512;
  float iv = sigmoid_f(g[d]);
  float fv = sigmoid_f(g[128 + d]);
  float gv = tanh_f(g[256 + d]);
  float ov = sigmoid_f(g[384 + d]);
  float c = fv * cprev[b * 128 + d] + iv * gv;
  float h = ov * tanh_f(c);
  out_h[b * 128 + d] = h;
  out_c[b * 128 + d] = c;
  st[d] = h; st[128 + d] = c;
  __syncthreads();
  float acc = Wsb[d];
  const float* wr = Wsw + d * 256;
#pragma unroll 4
  for (int k = 0; k < 256; ++k) acc += st[k] * wr[k];
  decf[b * 128 + d] = acc;
}

// ---------------------------------------------------------------------------
// K4 v2: e_t[b,t] = V_w . tanh(h_i@Wh^T + dec_f[b] + cov[b,t]*Wc)
// grid = B*4 = 2048 blocks (4 waves each), wave owns 32 t x all 128 d.
// ---------------------------------------------------------------------------
__global__ __launch_bounds__(256, 4) void k4_et(
    const float* __restrict__ h_i, const unsigned short* __restrict__ bw,
    const float* __restrict__ decf, const float* __restrict__ cov,
    const float* __restrict__ Wcw, const float* __restrict__ Vw,
    float* __restrict__ e_t) {
  const int b = blockIdx.x >> 2;
  const int q = blockIdx.x & 3;
  const int wv = threadIdx.x >> 6;
  const int lane = threadIdx.x & 63;
  const int lm = lane & 15, lg = lane >> 4;
  const int t0 = q * 128 + wv * 32;

  s16x4 afr[2][8];
#pragma unroll
  for (int mf = 0; mf < 2; ++mf) {
#pragma unroll
    for (int kf = 0; kf < 8; ++kf) {
      const float* p = h_i + (size_t)(b * 512 + t0 + mf * 16 + lm) * 128 + kf * 16 + lg * 4;
      f32x4 v = *(const f32x4*)p;
      s16x4 a; a[0] = f2bf(v[0]); a[1] = f2bf(v[1]); a[2] = f2bf(v[2]); a[3] = f2bf(v[3]);
      afr[mf][kf] = a;
    }
  }
  float dec_v[8], vw_v[8], wc_v[8];
#pragma unroll
  for (int nf = 0; nf < 8; ++nf) {
    dec_v[nf] = decf[b * 128 + nf * 16 + lm];
    vw_v[nf]  = Vw[nf * 16 + lm];
    wc_v[nf]  = Wcw[nf * 16 + lm];
  }
  float cov_v[8];
#pragma unroll
  for (int mf = 0; mf < 2; ++mf)
#pragma unroll
    for (int r = 0; r < 4; ++r)
      cov_v[mf * 4 + r] = cov[b * 512 + t0 + mf * 16 + lg * 4 + r];

  float e_acc[8];
#pragma unroll
  for (int i = 0; i < 8; ++i) e_acc[i] = 0.f;

  const f32x4 zf4 = {0.f, 0.f, 0.f, 0.f};
#pragma unroll
  for (int nf = 0; nf < 8; ++nf) {
    s16x4 bfr[8];
#pragma unroll
    for (int kf = 0; kf < 8; ++kf)
      bfr[kf] = *(const s16x4*)&bw[(((nf * 8 + kf) * 64) + lane) * 4];
    f32x4 acc0 = zf4, acc1 = zf4;
#pragma unroll
    for (int kf = 0; kf < 8; ++kf) {
      acc0 = __builtin_amdgcn_mfma_f32_16x16x16bf16_1k(afr[0][kf], bfr[kf], acc0, 0, 0, 0);
      acc1 = __builtin_amdgcn_mfma_f32_16x16x16bf16_1k(afr[1][kf], bfr[kf], acc1, 0, 0, 0);
    }
#pragma unroll
    for (int r = 0; r < 4; ++r) {
      float v0 = acc0[r] + dec_v[nf] + cov_v[r] * wc_v[nf];
      e_acc[r] += vw_v[nf] * tanh_f(v0);
      float v1 = acc1[r] + dec_v[nf] + cov_v[4 + r] * wc_v[nf];
      e_acc[4 + r] += vw_v[nf] * tanh_f(v1);
    }
  }
#pragma unroll
  for (int i = 0; i < 8; ++i) {
    float v = e_acc[i];
    v += __shfl_xor(v, 1); v += __shfl_xor(v, 2);
    v += __shfl_xor(v, 4); v += __shfl_xor(v, 8);
    e_acc[i] = v;
  }
  if (lm == 0) {
#pragma unroll
    for (int mf = 0; mf < 2; ++mf)
#pragma unroll
      for (int r = 0; r < 4; ++r)
        e_t[b * 512 + t0 + mf * 16 + lg * 4 + r] = e_acc[mf * 4 + r];
  }
}

// ---------------------------------------------------------------------------
// K5: softmax over t, coverage_new, ctx = sum_t a_t * h_i. One block per b.
// ---------------------------------------------------------------------------
__global__ __launch_bounds__(256) void k5_softmax_ctx(
    const float* __restrict__ e_t, const float* __restrict__ cov,
    const float* __restrict__ h_i, float* __restrict__ a_t,
    float* __restrict__ cov_out, float* __restrict__ ctx_out) {
  __shared__ float sm[512];
  __shared__ float red[1024];
  __shared__ float wred[8];
  int b = blockIdx.x, tid = threadIdx.x;
  float e0 = e_t[b * 512 + tid], e1 = e_t[b * 512 + 256 + tid];
  float m = fmaxf(e0, e1);
  for (int off = 32; off; off >>= 1) m = fmaxf(m, __shfl_xor(m, off));
  if ((tid & 63) == 0) wred[tid >> 6] = m;
  __syncthreads();
  m = fmaxf(fmaxf(wred[0], wred[1]), fmaxf(wred[2], wred[3]));
  float x0 = exp2f((e0 - m) * L2E);
  float x1v = exp2f((e1 - m) * L2E);
  float s = x0 + x1v;
  for (int off = 32; off; off >>= 1) s += __shfl_xor(s, off);
  if ((tid & 63) == 0) wred[4 + (tid >> 6)] = s;
  __syncthreads();
  s = wred[4] + wred[5] + wred[6] + wred[7];
  float inv = 1.f / s;
  float a0 = x0 * inv, a1 = x1v * inv;
  a_t[b * 512 + tid] = a0;
  a_t[b * 512 + 256 + tid] = a1;
  cov_out[b * 512 + tid] = cov[b * 512 + tid] + a0;
  cov_out[b * 512 + 256 + tid] = cov[b * 512 + 256 + tid] + a1;
  sm[tid] = a0; sm[256 + tid] = a1;
  __syncthreads();
  int j = tid & 31, tg = tid >> 5;
  const float* hb = h_i + (size_t)b * 512 * 128 + j * 4;
  f32x4 acc = {0.f, 0.f, 0.f, 0.f};
#pragma unroll 8
  for (int t = tg; t < 512; t += 8) {
    float a = sm[t];
    f32x4 hv = *(const f32x4*)(hb + (size_t)t * 128);
    acc += hv * a;
  }
  *(f32x4*)&red[tid * 4] = acc;
  __syncthreads();
  if (tid < 128) {
    float sacc = 0.f;
#pragma unroll
    for (int g = 0; g < 8; ++g) sacc += red[g * 128 + tid];
    ctx_out[b * 128 + tid] = sacc;
  }
}

// ---------------------------------------------------------------------------
// K6: pv1(bf16) = [h|ctx]@V1^T + V1_b ; p_gen ; attn_dist = (1-p_gen)*a_t
// ---------------------------------------------------------------------------
__global__ __launch_bounds__(256) void k6_pv1_pgen(
    const float* __restrict__ out_h, const float* __restrict__ out_c,
    const float* __restrict__ ctx, const float* __restrict__ emb,
    const int* __restrict__ x, const float* __restrict__ V1w,
    const float* __restrict__ V1b, const float* __restrict__ W2w,
    const float* __restrict__ W2b, const float* __restrict__ a_t,
    unsigned short* __restrict__ pv1bf, float* __restrict__ pgen,
    float* __restrict__ attn_out) {
  __shared__ float cat[896];  // [ctx(128) | h(128) | c(128) | xe(512)]
  __shared__ float wr_[4];
  int b = blockIdx.x, tid = threadIdx.x;
  if (tid < 128) {
    cat[tid] = ctx[b * 128 + tid];
    cat[128 + tid] = out_h[b * 128 + tid];
  } else {
    int q = tid - 128;
    cat[256 + q] = out_c[b * 128 + q];
  }
  int xb = x[b];
  for (int k = tid; k < 512; k += 256) cat[384 + k] = emb[xb * 512 + k];
  __syncthreads();
  for (int f = tid; f < 384; f += 256) {
    const float* w = V1w + f * 256;
    float acc = V1b[f];
#pragma unroll 4
    for (int k = 0; k < 256; ++k) {
      float av = (k < 128) ? cat[128 + k] : cat[k - 128];
      acc += av * w[k];
    }
    pv1bf[b * 384 + f] = (unsigned short)f2bf(acc);
  }
  float p = 0.f;
  for (int k = tid; k < 896; k += 256) p += cat[k] * W2w[k];
  for (int off = 32; off; off >>= 1) p += __shfl_xor(p, off);
  if ((tid & 63) == 0) wr_[tid >> 6] = p;
  __syncthreads();
  float pg = sigmoid_f(wr_[0] + wr_[1] + wr_[2] + wr_[3] + W2b[0]);
  if (tid == 0) pgen[b] = pg;
  float om = 1.f - pg;
  attn_out[b * 512 + tid]       = om * a_t[b * 512 + tid];
  attn_out[b * 512 + 256 + tid] = om * a_t[b * 512 + 256 + tid];
}

// ---------------------------------------------------------------------------
// K7 v4: logits = pv1 @ V2_w^T + V2_b -> d_out (stride VEXT_).
// High arithmetic intensity per wave: 64 rows x 64 cols, K=32 MFMA
// (mfma_f32_16x16x32_bf16, 16B operand loads), acc 4x4xf32x4 = 64 AGPRs.
// B = V2_w read DIRECTLY (f32, converted in-wave; read <= 2x total).
// No LDS, no barrier. grid = 944: q -> nb = (q>>4)*8 + (q&7), rh = (q>>3)&1;
// both row-halves of a panel share q%8 -> same XCD (B L2 reuse).
// Per wave: 144 x 16B loads : 192 MFMA (1.3 MFMA/load; was 0.8 w/ 8B loads).
// ---------------------------------------------------------------------------
__global__ __launch_bounds__(256) void k7_vocab(
    const unsigned short* __restrict__ pv1bf, const float* __restrict__ V2w,
    const float* __restrict__ V2b, float* __restrict__ outF) {
  const int q = blockIdx.x;
  const int nb = ((q >> 4) << 3) + (q & 7);
  const int rh = (q >> 3) & 1;
  if (nb >= 469) return;
  const int v0 = nb * 64;
  const int tid = threadIdx.x;
  const int wv = tid >> 6, lane = tid & 63;
  const int lm = lane & 15, lg = lane >> 4;
  const int r0 = rh * 256 + wv * 64;

  const f32x4 zf4 = {0.f, 0.f, 0.f, 0.f};
  f32x4 acc[4][4];  // [m (16-row tile)][nf (16-col tile)]
#pragma unroll
  for (int m = 0; m < 4; ++m)
#pragma unroll
    for (int nf = 0; nf < 4; ++nf) acc[m][nf] = zf4;

  int vrow[4]; bool vok[4];
#pragma unroll
  for (int nf = 0; nf < 4; ++nf) {
    int v = v0 + nf * 16 + lm;
    vok[nf] = (v < VOC_);
    vrow[nf] = vok[nf] ? v : (VOC_ - 1);
  }

#pragma unroll
  for (int kf = 0; kf < 12; ++kf) {
    // A fragments: 4 x s16x8 (pv1 is 384 KB, L2-hot)
    s16x8 afr[4];
#pragma unroll
    for (int m = 0; m < 4; ++m)
      afr[m] = *(const s16x8*)&pv1bf[(r0 + m * 16 + lm) * 384 + kf * 32 + lg * 8];
    // B fragments: 4 x (2 x f32x4 -> cvt -> s16x8)
    s16x8 bfr[4];
#pragma unroll
    for (int nf = 0; nf < 4; ++nf) {
      const float* p = V2w + (size_t)vrow[nf] * 384 + kf * 32 + lg * 8;
      f32x4 w0 = *(const f32x4*)p;
      f32x4 w1 = *(const f32x4*)(p + 4);
      if (!vok[nf]) { w0 = zf4; w1 = zf4; }
      s16x8 bb;
      bb[0] = f2bf(w0[0]); bb[1] = f2bf(w0[1]); bb[2] = f2bf(w0[2]); bb[3] = f2bf(w0[3]);
      bb[4] = f2bf(w1[0]); bb[5] = f2bf(w1[1]); bb[6] = f2bf(w1[2]); bb[7] = f2bf(w1[3]);
      bfr[nf] = bb;
    }
#pragma unroll
    for (int m = 0; m < 4; ++m)
#pragma unroll
      for (int nf = 0; nf < 4; ++nf)
        acc[m][nf] = __builtin_amdgcn_mfma_f32_16x16x32_bf16(afr[m], bfr[nf], acc[m][nf], 0, 0, 0);
  }

  // D[i=4*lg+r][j=lm]: row = r0 + m*16 + lg*4 + r, vcol = v0 + nf*16 + lm
#pragma unroll
  for (int nf = 0; nf < 4; ++nf) {
    int vcol = v0 + nf * 16 + lm;
    if (vcol < VOC_) {
      float bias = V2b[vcol];
#pragma unroll
      for (int m = 0; m < 4; ++m) {
        int rbase = r0 + m * 16 + lg * 4;
#pragma unroll
        for (int r = 0; r < 4; ++r)
          outF[(size_t)(rbase + r) * VEXT_ + vcol] = acc[m][nf][r] + bias;
      }
    }
  }
}

// ---------------------------------------------------------------------------
// K8: per-row softmax of logits (in d_out), scale by p_gen, zero the 50 OOV
// cols, scatter-add attn_dist with WORKGROUP-scope atomics. One block per b.
// ---------------------------------------------------------------------------
#define K8_IT 30  // ceil(VOC_/1024)

__global__ __launch_bounds__(1024) void k8_final(
    const float* __restrict__ pgen, const int* __restrict__ code_ext,
    const float* __restrict__ attn, float* __restrict__ outF) {
  __shared__ float lm_[16], ls_[16];
  const int b = blockIdx.x, tid = threadIdx.x;
  float* row = outF + (size_t)b * VEXT_;

  float lv[K8_IT];
#pragma unroll
  for (int i = 0; i < K8_IT; ++i) {
    int v = tid + i * 1024;
    lv[i] = (v < VOC_) ? row[v] : -3.4e38f;
  }
  float m = lv[0];
#pragma unroll
  for (int i = 1; i < K8_IT; ++i) m = fmaxf(m, lv[i]);
  for (int off = 32; off; off >>= 1) m = fmaxf(m, __shfl_xor(m, off));
  if ((tid & 63) == 0) lm_[tid >> 6] = m;
  __syncthreads();
  float M = lm_[0];
#pragma unroll
  for (int i = 1; i < 16; ++i) M = fmaxf(M, lm_[i]);
  float s = 0.f;
#pragma unroll
  for (int i = 0; i < K8_IT; ++i) {
    lv[i] = exp2f((lv[i] - M) * L2E);
    s += lv[i];
  }
  for (int off = 32; off; off >>= 1) s += __shfl_xor(s, off);
  if ((tid & 63) == 0) ls_[tid >> 6] = s;
  __syncthreads();
  float S = 0.f;
#pragma unroll
  for (int i = 0; i < 16; ++i) S += ls_[i];
  float pm = pgen[b] / S;
#pragma unroll
  for (int i = 0; i < K8_IT; ++i) {
    int v = tid + i * 1024;
    if (v < VOC_) row[v] = pm * lv[i];
  }
  if (tid < 50) row[VOC_ + tid] = 0.f;
  __syncthreads();  // drains vmcnt: all row stores are at the local L2
  if (tid < 512) {
    int idx = code_ext[b * 512 + tid];
    __hip_atomic_fetch_add(&row[idx], attn[b * 512 + tid],
                           __ATOMIC_RELAXED, __HIP_MEMORY_SCOPE_WORKGROUP);
  }
}

// ---------------------------------------------------------------------------
extern "C" void kernel_launch(void* const* d_in, const int* in_sizes, int n_in,
                              void* d_out, int out_size, void* d_ws, size_t ws_size,
                              hipStream_t stream) {
  (void)in_sizes; (void)n_in; (void)out_size; (void)ws_size;
  const float* h_i    = (const float*)d_in[0];
  const float* h_prev = (const float*)d_in[1];
  const float* c_prev = (const float*)d_in[2];
  const float* ctxp   = (const float*)d_in[3];
  const float* cov    = (const float*)d_in[4];
  const float* emb    = (const float*)d_in[5];
  const float* Wih    = (const float*)d_in[6];
  const float* Whh    = (const float*)d_in[7];
  const float* bih    = (const float*)d_in[8];
  const float* bhh    = (const float*)d_in[9];
  const float* W1w    = (const float*)d_in[10];
  const float* W1b    = (const float*)d_in[11];
  const float* W2w    = (const float*)d_in[12];
  const float* W2b    = (const float*)d_in[13];
  const float* V1w    = (const float*)d_in[14];
  const float* V1b    = (const float*)d_in[15];
  const float* V2w    = (const float*)d_in[16];
  const float* V2b    = (const float*)d_in[17];
  const float* Whw    = (const float*)d_in[18];
  const float* Wsw    = (const float*)d_in[19];
  const float* Wsb    = (const float*)d_in[20];
  const float* Wcw    = (const float*)d_in[21];
  const float* Vw     = (const float*)d_in[22];
  const int*   x      = (const int*)d_in[23];
  const int*   code   = (const int*)d_in[24];

  float* ws    = (float*)d_ws;
  float* x1    = ws;                 // 262144
  float* gates = ws + 262144;        // 262144
  float* decf  = ws + 524288;        // 65536
  float* e_t   = ws + 589824;        // 262144
  float* a_t   = ws + 851968;        // 262144
  unsigned short* pv1bf = (unsigned short*)(ws + 1114112);  // 196608 shorts
  float* pgen  = ws + 1212416;       // 512
  // bw (bf16 Wh_w fragments) aliases the a_t region: bw lives k0..k4; a_t is
  // first written in k5. No overlap in time.
  unsigned short* bw = (unsigned short*)(ws + 851968);

  float* outF  = (float*)d_out;                    // final_dist 512 x 30051
  float* attn  = outF + (size_t)512 * VEXT_;       // 262144
  float* o_h   = attn + 262144;                    // 65536
  float* o_c   = o_h + 65536;                      // 65536
  float* o_cov = o_c + 65536;                      // 262144
  float* o_ctx = o_cov + 262144;                   // 65536

  k0_prep<<<1, 256, 0, stream>>>(Whw, bw);
  k1_x1<<<dim3(16, 16), 256, 0, stream>>>(emb, x, ctxp, W1w, W1b, x1);
  k2_gates<<<dim3(16, 16), 256, 0, stream>>>(x1, h_prev, Wih, Whh, bih, bhh, gates);
  k3_lstm<<<512, 128, 0, stream>>>(gates, c_prev, Wsw, Wsb, o_h, o_c, decf);
  k4_et<<<2048, 256, 0, stream>>>(h_i, bw, decf, cov, Wcw, Vw, e_t);
  k5_softmax_ctx<<<512, 256, 0, stream>>>(e_t, cov, h_i, a_t, o_cov, o_ctx);
  k6_pv1_pgen<<<512, 256, 0, stream>>>(o_h, o_c, o_ctx, emb, x, V1w, V1b, W2w, W2b,
                                       a_t, pv1bf, pgen, attn);
  k7_vocab<<<944, 256, 0, stream>>>(pv1bf, V2w, V2b, outF);
  k8_final<<<512, 1024, 0, stream>>>(pgen, code, attn, outF);
}

// Round 7
// 288.797 us; speedup vs baseline: 1.1128x; 1.0435x over previous
//
#include <hip/hip_runtime.h>
#include <math.h>

// Shapes (fixed by the reference)
#define B_    512
#define T_    512
#define DEC_  128
#define EMB_  512
#define VOC_  30001
#define VEXT_ 30051   // VOC_ + 50 OOV

typedef float f32x4 __attribute__((ext_vector_type(4)));
typedef short s16x4 __attribute__((ext_vector_type(4)));
typedef short s16x8 __attribute__((ext_vector_type(8)));

#define L2E 1.4426950408889634f

__device__ __forceinline__ float sigmoid_f(float x) {
  float xc = fminf(fmaxf(x, -30.f), 30.f);
  float t = exp2f(xc * L2E);
  return t / (1.f + t);
}
__device__ __forceinline__ float tanh_f(float x) {
  float xc = fminf(fmaxf(x, -15.f), 15.f);
  float t = exp2f(xc * (2.f * L2E));
  return (t - 1.f) / (t + 1.f);
}
// f32 -> bf16 (RNE)
__device__ __forceinline__ short f2bf(float f) {
  unsigned u = __builtin_bit_cast(unsigned, f);
  u += 0x7FFFu + ((u >> 16) & 1u);
  return (short)(u >> 16);
}
__device__ __forceinline__ float bf2f(unsigned short h) {
  return __builtin_bit_cast(float, (unsigned)h << 16);
}
// 128B-aligned bf16 logits base for row b, inside row b's own d_out slot.
__device__ __forceinline__ unsigned short* logit_row(float* outF, int b) {
  size_t byteoff = ((size_t)b * VEXT_ * 4 + 127) & ~(size_t)127;
  return (unsigned short*)((char*)outF + byteoff);
}

// ---------------------------------------------------------------------------
// K0: convert Wh_w (128x128 f32) to bf16 MFMA B-fragments, fragment-linear:
// bw[((nf*8+kf)*64 + lane)*4 + e] = Whw[nf*16 + (lane&15)][kf*16 + (lane>>4)*4 + e]
// ---------------------------------------------------------------------------
__global__ __launch_bounds__(256) void k0_prep(
    const float* __restrict__ Whw, unsigned short* __restrict__ bw) {
  const int t = threadIdx.x;
#pragma unroll
  for (int i = 0; i < 16; ++i) {
    int p = t + 256 * i;          // (frag, lane) pair
    int f = p >> 6, l = p & 63;
    int nf = f >> 3, kf = f & 7;
    int rowN = nf * 16 + (l & 15);
    int colK = kf * 16 + (l >> 4) * 4;
    f32x4 w = *(const f32x4*)(Whw + rowN * 128 + colK);
    s16x4 bb; bb[0] = f2bf(w[0]); bb[1] = f2bf(w[1]); bb[2] = f2bf(w[2]); bb[3] = f2bf(w[3]);
    *(s16x4*)&bw[p * 4] = bb;
  }
}

// ---------------------------------------------------------------------------
// K1: x1[b,f] = sum_k [emb[x[b]] | ctx_prev][b,k] * W1_w[f,k] + W1_b[f]
// ---------------------------------------------------------------------------
__global__ __launch_bounds__(256) void k1_x1(
    const float* __restrict__ emb, const int* __restrict__ x,
    const float* __restrict__ ctxp, const float* __restrict__ W1w,
    const float* __restrict__ W1b, float* __restrict__ x1) {
  __shared__ float As[32][33];
  __shared__ float Ws[32][33];
  const int tid = threadIdx.x;
  const int f0 = blockIdx.x * 32, b0 = blockIdx.y * 32;
  const int row = tid >> 3, seg = tid & 7;
  const int tx = tid & 15, ty = tid >> 4;
  float a00 = 0.f, a01 = 0.f, a10 = 0.f, a11 = 0.f;
  for (int k0 = 0; k0 < 640; k0 += 32) {
    int k = k0 + seg * 4;
    f32x4 av;
    if (k < 512) {
      int xb = x[b0 + row];
      av = *(const f32x4*)(emb + xb * 512 + k);
    } else {
      av = *(const f32x4*)(ctxp + (b0 + row) * 128 + (k - 512));
    }
    As[row][seg * 4 + 0] = av[0]; As[row][seg * 4 + 1] = av[1];
    As[row][seg * 4 + 2] = av[2]; As[row][seg * 4 + 3] = av[3];
    f32x4 wv = *(const f32x4*)(W1w + (f0 + row) * 640 + k);
    Ws[row][seg * 4 + 0] = wv[0]; Ws[row][seg * 4 + 1] = wv[1];
    Ws[row][seg * 4 + 2] = wv[2]; Ws[row][seg * 4 + 3] = wv[3];
    __syncthreads();
#pragma unroll
    for (int kk = 0; kk < 32; ++kk) {
      float v0 = As[ty * 2][kk], v1 = As[ty * 2 + 1][kk];
      float w0 = Ws[tx * 2][kk], w1 = Ws[tx * 2 + 1][kk];
      a00 += v0 * w0; a01 += v0 * w1; a10 += v1 * w0; a11 += v1 * w1;
    }
    __syncthreads();
  }
  int fo = f0 + tx * 2, bo = b0 + ty * 2;
  x1[bo * 512 + fo]           = a00 + W1b[fo];
  x1[bo * 512 + fo + 1]       = a01 + W1b[fo + 1];
  x1[(bo + 1) * 512 + fo]     = a10 + W1b[fo];
  x1[(bo + 1) * 512 + fo + 1] = a11 + W1b[fo + 1];
}

// ---------------------------------------------------------------------------
// K2: gates[b,j] = sum [x1 | h_prev][b,k] * [W_ih | W_hh][j,k] + b_ih + b_hh
// ---------------------------------------------------------------------------
__global__ __launch_bounds__(256) void k2_gates(
    const float* __restrict__ x1, const float* __restrict__ hprev,
    const float* __restrict__ Wih, const float* __restrict__ Whh,
    const float* __restrict__ bih, const float* __restrict__ bhh,
    float* __restrict__ gates) {
  __shared__ float As[32][33];
  __shared__ float Ws[32][33];
  const int tid = threadIdx.x;
  const int f0 = blockIdx.x * 32, b0 = blockIdx.y * 32;
  const int row = tid >> 3, seg = tid & 7;
  const int tx = tid & 15, ty = tid >> 4;
  float a00 = 0.f, a01 = 0.f, a10 = 0.f, a11 = 0.f;
  for (int k0 = 0; k0 < 640; k0 += 32) {
    int k = k0 + seg * 4;
    f32x4 av, wv;
    if (k < 512) {
      av = *(const f32x4*)(x1 + (b0 + row) * 512 + k);
      wv = *(const f32x4*)(Wih + (f0 + row) * 512 + k);
    } else {
      av = *(const f32x4*)(hprev + (b0 + row) * 128 + (k - 512));
      wv = *(const f32x4*)(Whh + (f0 + row) * 128 + (k - 512));
    }
    As[row][seg * 4 + 0] = av[0]; As[row][seg * 4 + 1] = av[1];
    As[row][seg * 4 + 2] = av[2]; As[row][seg * 4 + 3] = av[3];
    Ws[row][seg * 4 + 0] = wv[0]; Ws[row][seg * 4 + 1] = wv[1];
    Ws[row][seg * 4 + 2] = wv[2]; Ws[row][seg * 4 + 3] = wv[3];
    __syncthreads();
#pragma unroll
    for (int kk = 0; kk < 32; ++kk) {
      float v0 = As[ty * 2][kk], v1 = As[ty * 2 + 1][kk];
      float w0 = Ws[tx * 2][kk], w1 = Ws[tx * 2 + 1][kk];
      a00 += v0 * w0; a01 += v0 * w1; a10 += v1 * w0; a11 += v1 * w1;
    }
    __syncthreads();
  }
  int fo = f0 + tx * 2, bo = b0 + ty * 2;
  gates[bo * 512 + fo]           = a00 + bih[fo] + bhh[fo];
  gates[bo * 512 + fo + 1]       = a01 + bih[fo + 1] + bhh[fo + 1];
  gates[(bo + 1) * 512 + fo]     = a10 + bih[fo] + bhh[fo];
  gates[(bo + 1) * 512 + fo + 1] = a11 + bih[fo + 1] + bhh[fo + 1];
}

// ---------------------------------------------------------------------------
// K3: LSTM cell + dec_f = s_t @ Ws_w^T + Ws_b.  One block per b, 128 threads.
// ---------------------------------------------------------------------------
__global__ __launch_bounds__(128) void k3_lstm(
    const float* __restrict__ gates, const float* __restrict__ cprev,
    const float* __restrict__ Wsw, const float* __restrict__ Wsb,
    float* __restrict__ out_h, float* __restrict__ out_c,
    float* __restrict__ decf) {
  __shared__ float st[256];
  int b = blockIdx.x, d = threadIdx.x;
  const float* g = gates + b * 512;
  float iv = sigmoid_f(g[d]);
  float fv = sigmoid_f(g[128 + d]);
  float gv = tanh_f(g[256 + d]);
  float ov = sigmoid_f(g[384 + d]);
  float c = fv * cprev[b * 128 + d] + iv * gv;
  float h = ov * tanh_f(c);
  out_h[b * 128 + d] = h;
  out_c[b * 128 + d] = c;
  st[d] = h; st[128 + d] = c;
  __syncthreads();
  float acc = Wsb[d];
  const float* wr = Wsw + d * 256;
#pragma unroll 4
  for (int k = 0; k < 256; ++k) acc += st[k] * wr[k];
  decf[b * 128 + d] = acc;
}

// ---------------------------------------------------------------------------
// K4 v2: e_t[b,t] = V_w . tanh(h_i@Wh^T + dec_f[b] + cov[b,t]*Wc)
// grid = B*4 = 2048 blocks (4 waves each), wave owns 32 t x all 128 d.
// ---------------------------------------------------------------------------
__global__ __launch_bounds__(256, 4) void k4_et(
    const float* __restrict__ h_i, const unsigned short* __restrict__ bw,
    const float* __restrict__ decf, const float* __restrict__ cov,
    const float* __restrict__ Wcw, const float* __restrict__ Vw,
    float* __restrict__ e_t) {
  const int b = blockIdx.x >> 2;
  const int q = blockIdx.x & 3;
  const int wv = threadIdx.x >> 6;
  const int lane = threadIdx.x & 63;
  const int lm = lane & 15, lg = lane >> 4;
  const int t0 = q * 128 + wv * 32;

  s16x4 afr[2][8];
#pragma unroll
  for (int mf = 0; mf < 2; ++mf) {
#pragma unroll
    for (int kf = 0; kf < 8; ++kf) {
      const float* p = h_i + (size_t)(b * 512 + t0 + mf * 16 + lm) * 128 + kf * 16 + lg * 4;
      f32x4 v = *(const f32x4*)p;
      s16x4 a; a[0] = f2bf(v[0]); a[1] = f2bf(v[1]); a[2] = f2bf(v[2]); a[3] = f2bf(v[3]);
      afr[mf][kf] = a;
    }
  }
  float dec_v[8], vw_v[8], wc_v[8];
#pragma unroll
  for (int nf = 0; nf < 8; ++nf) {
    dec_v[nf] = decf[b * 128 + nf * 16 + lm];
    vw_v[nf]  = Vw[nf * 16 + lm];
    wc_v[nf]  = Wcw[nf * 16 + lm];
  }
  float cov_v[8];
#pragma unroll
  for (int mf = 0; mf < 2; ++mf)
#pragma unroll
    for (int r = 0; r < 4; ++r)
      cov_v[mf * 4 + r] = cov[b * 512 + t0 + mf * 16 + lg * 4 + r];

  float e_acc[8];
#pragma unroll
  for (int i = 0; i < 8; ++i) e_acc[i] = 0.f;

  const f32x4 zf4 = {0.f, 0.f, 0.f, 0.f};
#pragma unroll
  for (int nf = 0; nf < 8; ++nf) {
    s16x4 bfr[8];
#pragma unroll
    for (int kf = 0; kf < 8; ++kf)
      bfr[kf] = *(const s16x4*)&bw[(((nf * 8 + kf) * 64) + lane) * 4];
    f32x4 acc0 = zf4, acc1 = zf4;
#pragma unroll
    for (int kf = 0; kf < 8; ++kf) {
      acc0 = __builtin_amdgcn_mfma_f32_16x16x16bf16_1k(afr[0][kf], bfr[kf], acc0, 0, 0, 0);
      acc1 = __builtin_amdgcn_mfma_f32_16x16x16bf16_1k(afr[1][kf], bfr[kf], acc1, 0, 0, 0);
    }
#pragma unroll
    for (int r = 0; r < 4; ++r) {
      float v0 = acc0[r] + dec_v[nf] + cov_v[r] * wc_v[nf];
      e_acc[r] += vw_v[nf] * tanh_f(v0);
      float v1 = acc1[r] + dec_v[nf] + cov_v[4 + r] * wc_v[nf];
      e_acc[4 + r] += vw_v[nf] * tanh_f(v1);
    }
  }
#pragma unroll
  for (int i = 0; i < 8; ++i) {
    float v = e_acc[i];
    v += __shfl_xor(v, 1); v += __shfl_xor(v, 2);
    v += __shfl_xor(v, 4); v += __shfl_xor(v, 8);
    e_acc[i] = v;
  }
  if (lm == 0) {
#pragma unroll
    for (int mf = 0; mf < 2; ++mf)
#pragma unroll
      for (int r = 0; r < 4; ++r)
        e_t[b * 512 + t0 + mf * 16 + lg * 4 + r] = e_acc[mf * 4 + r];
  }
}

// ---------------------------------------------------------------------------
// K5: softmax over t, coverage_new, ctx = sum_t a_t * h_i. One block per b.
// ---------------------------------------------------------------------------
__global__ __launch_bounds__(256) void k5_softmax_ctx(
    const float* __restrict__ e_t, const float* __restrict__ cov,
    const float* __restrict__ h_i, float* __restrict__ a_t,
    float* __restrict__ cov_out, float* __restrict__ ctx_out) {
  __shared__ float sm[512];
  __shared__ float red[1024];
  __shared__ float wred[8];
  int b = blockIdx.x, tid = threadIdx.x;
  float e0 = e_t[b * 512 + tid], e1 = e_t[b * 512 + 256 + tid];
  float m = fmaxf(e0, e1);
  for (int off = 32; off; off >>= 1) m = fmaxf(m, __shfl_xor(m, off));
  if ((tid & 63) == 0) wred[tid >> 6] = m;
  __syncthreads();
  m = fmaxf(fmaxf(wred[0], wred[1]), fmaxf(wred[2], wred[3]));
  float x0 = exp2f((e0 - m) * L2E);
  float x1v = exp2f((e1 - m) * L2E);
  float s = x0 + x1v;
  for (int off = 32; off; off >>= 1) s += __shfl_xor(s, off);
  if ((tid & 63) == 0) wred[4 + (tid >> 6)] = s;
  __syncthreads();
  s = wred[4] + wred[5] + wred[6] + wred[7];
  float inv = 1.f / s;
  float a0 = x0 * inv, a1 = x1v * inv;
  a_t[b * 512 + tid] = a0;
  a_t[b * 512 + 256 + tid] = a1;
  cov_out[b * 512 + tid] = cov[b * 512 + tid] + a0;
  cov_out[b * 512 + 256 + tid] = cov[b * 512 + 256 + tid] + a1;
  sm[tid] = a0; sm[256 + tid] = a1;
  __syncthreads();
  int j = tid & 31, tg = tid >> 5;
  const float* hb = h_i + (size_t)b * 512 * 128 + j * 4;
  f32x4 acc = {0.f, 0.f, 0.f, 0.f};
#pragma unroll 8
  for (int t = tg; t < 512; t += 8) {
    float a = sm[t];
    f32x4 hv = *(const f32x4*)(hb + (size_t)t * 128);
    acc += hv * a;
  }
  *(f32x4*)&red[tid * 4] = acc;
  __syncthreads();
  if (tid < 128) {
    float sacc = 0.f;
#pragma unroll
    for (int g = 0; g < 8; ++g) sacc += red[g * 128 + tid];
    ctx_out[b * 128 + tid] = sacc;
  }
}

// ---------------------------------------------------------------------------
// K6: pv1(bf16) = [h|ctx]@V1^T + V1_b ; p_gen ; attn_dist = (1-p_gen)*a_t
// ---------------------------------------------------------------------------
__global__ __launch_bounds__(256) void k6_pv1_pgen(
    const float* __restrict__ out_h, const float* __restrict__ out_c,
    const float* __restrict__ ctx, const float* __restrict__ emb,
    const int* __restrict__ x, const float* __restrict__ V1w,
    const float* __restrict__ V1b, const float* __restrict__ W2w,
    const float* __restrict__ W2b, const float* __restrict__ a_t,
    unsigned short* __restrict__ pv1bf, float* __restrict__ pgen,
    float* __restrict__ attn_out) {
  __shared__ float cat[896];  // [ctx(128) | h(128) | c(128) | xe(512)]
  __shared__ float wr_[4];
  int b = blockIdx.x, tid = threadIdx.x;
  if (tid < 128) {
    cat[tid] = ctx[b * 128 + tid];
    cat[128 + tid] = out_h[b * 128 + tid];
  } else {
    int q = tid - 128;
    cat[256 + q] = out_c[b * 128 + q];
  }
  int xb = x[b];
  for (int k = tid; k < 512; k += 256) cat[384 + k] = emb[xb * 512 + k];
  __syncthreads();
  for (int f = tid; f < 384; f += 256) {
    const float* w = V1w + f * 256;
    float acc = V1b[f];
#pragma unroll 4
    for (int k = 0; k < 256; ++k) {
      float av = (k < 128) ? cat[128 + k] : cat[k - 128];
      acc += av * w[k];
    }
    pv1bf[b * 384 + f] = (unsigned short)f2bf(acc);
  }
  float p = 0.f;
  for (int k = tid; k < 896; k += 256) p += cat[k] * W2w[k];
  for (int off = 32; off; off >>= 1) p += __shfl_xor(p, off);
  if ((tid & 63) == 0) wr_[tid >> 6] = p;
  __syncthreads();
  float pg = sigmoid_f(wr_[0] + wr_[1] + wr_[2] + wr_[3] + W2b[0]);
  if (tid == 0) pgen[b] = pg;
  float om = 1.f - pg;
  attn_out[b * 512 + tid]       = om * a_t[b * 512 + tid];
  attn_out[b * 512 + 256 + tid] = om * a_t[b * 512 + 256 + tid];
}

// ---------------------------------------------------------------------------
// K7 v5: logits (bf16) = pv1 @ V2_w^T + V2_b -> 128B-aligned region inside
// each d_out row slot. Compute identical to v4 (64x64/wave, K=32 MFMA,
// direct V2w reads). Epilogue: per-wave LDS transpose (32x65 f32, 2 passes)
// -> packed s16x4 stores where each instruction writes 4 rows x 128B FULL
// cache lines (aligned: base 128B-aligned, v0 multiple of 64 -> 128B).
// ---------------------------------------------------------------------------
__global__ __launch_bounds__(256) void k7_vocab(
    const unsigned short* __restrict__ pv1bf, const float* __restrict__ V2w,
    const float* __restrict__ V2b, float* __restrict__ outF) {
  __shared__ float lt[4][32 * 65];  // per-wave transpose tile (33.3 KB total)
  const int q = blockIdx.x;
  const int nb = ((q >> 4) << 3) + (q & 7);
  const int rh = (q >> 3) & 1;
  if (nb >= 469) return;
  const int v0 = nb * 64;
  const int tid = threadIdx.x;
  const int wv = tid >> 6, lane = tid & 63;
  const int lm = lane & 15, lg = lane >> 4;
  const int r0 = rh * 256 + wv * 64;

  const f32x4 zf4 = {0.f, 0.f, 0.f, 0.f};
  f32x4 acc[4][4];  // [m (16-row tile)][nf (16-col tile)]
#pragma unroll
  for (int m = 0; m < 4; ++m)
#pragma unroll
    for (int nf = 0; nf < 4; ++nf) acc[m][nf] = zf4;

  int vrow[4]; bool vok[4];
#pragma unroll
  for (int nf = 0; nf < 4; ++nf) {
    int v = v0 + nf * 16 + lm;
    vok[nf] = (v < VOC_);
    vrow[nf] = vok[nf] ? v : (VOC_ - 1);
  }

#pragma unroll
  for (int kf = 0; kf < 12; ++kf) {
    s16x8 afr[4];
#pragma unroll
    for (int m = 0; m < 4; ++m)
      afr[m] = *(const s16x8*)&pv1bf[(r0 + m * 16 + lm) * 384 + kf * 32 + lg * 8];
    s16x8 bfr[4];
#pragma unroll
    for (int nf = 0; nf < 4; ++nf) {
      const float* p = V2w + (size_t)vrow[nf] * 384 + kf * 32 + lg * 8;
      f32x4 w0 = *(const f32x4*)p;
      f32x4 w1 = *(const f32x4*)(p + 4);
      if (!vok[nf]) { w0 = zf4; w1 = zf4; }
      s16x8 bb;
      bb[0] = f2bf(w0[0]); bb[1] = f2bf(w0[1]); bb[2] = f2bf(w0[2]); bb[3] = f2bf(w0[3]);
      bb[4] = f2bf(w1[0]); bb[5] = f2bf(w1[1]); bb[6] = f2bf(w1[2]); bb[7] = f2bf(w1[3]);
      bfr[nf] = bb;
    }
#pragma unroll
    for (int m = 0; m < 4; ++m)
#pragma unroll
      for (int nf = 0; nf < 4; ++nf)
        acc[m][nf] = __builtin_amdgcn_mfma_f32_16x16x32_bf16(afr[m], bfr[nf], acc[m][nf], 0, 0, 0);
  }

  // bias (0 for padded cols -> stores benign zeros k8 ignores)
  float bias[4];
#pragma unroll
  for (int nf = 0; nf < 4; ++nf)
    bias[nf] = vok[nf] ? V2b[v0 + nf * 16 + lm] : 0.f;

  // Epilogue: two passes of 32 rows through the wave-private LDS tile.
  float* T = lt[wv];
  const int rq = lane >> 4, cq = lane & 15;
#pragma unroll
  for (int p = 0; p < 2; ++p) {
#pragma unroll
    for (int mm = 0; mm < 2; ++mm) {
      int m = p * 2 + mm;
#pragma unroll
      for (int nf = 0; nf < 4; ++nf)
#pragma unroll
        for (int r = 0; r < 4; ++r)
          T[(mm * 16 + lg * 4 + r) * 65 + nf * 16 + lm] = acc[m][nf][r] + bias[nf];
    }
    // wave-private LDS: same-wave DS ordering + compiler lgkmcnt handles dep
#pragma unroll
    for (int it = 0; it < 8; ++it) {
      int trow = it * 4 + rq;
      f32x4 vv = *(const f32x4*)&T[trow * 65 + cq * 4];
      s16x4 hb;
      hb[0] = f2bf(vv[0]); hb[1] = f2bf(vv[1]); hb[2] = f2bf(vv[2]); hb[3] = f2bf(vv[3]);
      int orow = r0 + p * 32 + trow;
      unsigned short* dst = logit_row(outF, orow);
      *(s16x4*)&dst[v0 + cq * 4] = hb;
    }
  }
}

// ---------------------------------------------------------------------------
// K8: per-row softmax over bf16 logits (aligned region in d_out row slot),
// scale by p_gen, write f32 final_dist in place, zero 50 OOV cols,
// scatter-add attn_dist with WORKGROUP-scope atomics. One block per b.
// In-place safety: ALL logit reads complete (in registers) before the first
// __syncthreads(); all f32 writes happen after -> no read/write overlap.
// ---------------------------------------------------------------------------
#define K8_IT 30  // ceil(VOC_/1024)

__global__ __launch_bounds__(1024) void k8_final(
    const float* __restrict__ pgen, const int* __restrict__ code_ext,
    const float* __restrict__ attn, float* __restrict__ outF) {
  __shared__ float lm_[16], ls_[16];
  const int b = blockIdx.x, tid = threadIdx.x;
  float* row = outF + (size_t)b * VEXT_;
  const unsigned short* lrow = logit_row(outF, b);

  float lv[K8_IT];
#pragma unroll
  for (int i = 0; i < K8_IT; ++i) {
    int v = tid + i * 1024;
    lv[i] = (v < VOC_) ? bf2f(lrow[v]) : -3.4e38f;
  }
  float m = lv[0];
#pragma unroll
  for (int i = 1; i < K8_IT; ++i) m = fmaxf(m, lv[i]);
  for (int off = 32; off; off >>= 1) m = fmaxf(m, __shfl_xor(m, off));
  if ((tid & 63) == 0) lm_[tid >> 6] = m;
  __syncthreads();
  float M = lm_[0];
#pragma unroll
  for (int i = 1; i < 16; ++i) M = fmaxf(M, lm_[i]);
  float s = 0.f;
#pragma unroll
  for (int i = 0; i < K8_IT; ++i) {
    lv[i] = exp2f((lv[i] - M) * L2E);
    s += lv[i];
  }
  for (int off = 32; off; off >>= 1) s += __shfl_xor(s, off);
  if ((tid & 63) == 0) ls_[tid >> 6] = s;
  __syncthreads();
  float S = 0.f;
#pragma unroll
  for (int i = 0; i < 16; ++i) S += ls_[i];
  float pm = pgen[b] / S;
#pragma unroll
  for (int i = 0; i < K8_IT; ++i) {
    int v = tid + i * 1024;
    if (v < VOC_) row[v] = pm * lv[i];
  }
  if (tid < 50) row[VOC_ + tid] = 0.f;
  __syncthreads();  // drains vmcnt: all row stores are at the local L2
  if (tid < 512) {
    int idx = code_ext[b * 512 + tid];
    __hip_atomic_fetch_add(&row[idx], attn[b * 512 + tid],
                           __ATOMIC_RELAXED, __HIP_MEMORY_SCOPE_WORKGROUP);
  }
}

// ---------------------------------------------------------------------------
extern "C" void kernel_launch(void* const* d_in, const int* in_sizes, int n_in,
                              void* d_out, int out_size, void* d_ws, size_t ws_size,
                              hipStream_t stream) {
  (void)in_sizes; (void)n_in; (void)out_size; (void)ws_size;
  const float* h_i    = (const float*)d_in[0];
  const float* h_prev = (const float*)d_in[1];
  const float* c_prev = (const float*)d_in[2];
  const float* ctxp   = (const float*)d_in[3];
  const float* cov    = (const float*)d_in[4];
  const float* emb    = (const float*)d_in[5];
  const float* Wih    = (const float*)d_in[6];
  const float* Whh    = (const float*)d_in[7];
  const float* bih    = (const float*)d_in[8];
  const float* bhh    = (const float*)d_in[9];
  const float* W1w    = (const float*)d_in[10];
  const float* W1b    = (const float*)d_in[11];
  const float* W2w    = (const float*)d_in[12];
  const float* W2b    = (const float*)d_in[13];
  const float* V1w    = (const float*)d_in[14];
  const float* V1b    = (const float*)d_in[15];
  const float* V2w    = (const float*)d_in[16];
  const float* V2b    = (const float*)d_in[17];
  const float* Whw    = (const float*)d_in[18];
  const float* Wsw    = (const float*)d_in[19];
  const float* Wsb    = (const float*)d_in[20];
  const float* Wcw    = (const float*)d_in[21];
  const float* Vw     = (const float*)d_in[22];
  const int*   x      = (const int*)d_in[23];
  const int*   code   = (const int*)d_in[24];

  float* ws    = (float*)d_ws;
  float* x1    = ws;                 // 262144
  float* gates = ws + 262144;        // 262144
  float* decf  = ws + 524288;        // 65536
  float* e_t   = ws + 589824;        // 262144
  float* a_t   = ws + 851968;        // 262144
  unsigned short* pv1bf = (unsigned short*)(ws + 1114112);  // 196608 shorts
  float* pgen  = ws + 1212416;       // 512
  // bw (bf16 Wh_w fragments) aliases the a_t region: bw lives k0..k4; a_t is
  // first written in k5. No overlap in time.
  unsigned short* bw = (unsigned short*)(ws + 851968);

  float* outF  = (float*)d_out;                    // final_dist 512 x 30051
  float* attn  = outF + (size_t)512 * VEXT_;       // 262144
  float* o_h   = attn + 262144;                    // 65536
  float* o_c   = o_h + 65536;                      // 65536
  float* o_cov = o_c + 65536;                      // 262144
  float* o_ctx = o_cov + 262144;                   // 65536

  k0_prep<<<1, 256, 0, stream>>>(Whw, bw);
  k1_x1<<<dim3(16, 16), 256, 0, stream>>>(emb, x, ctxp, W1w, W1b, x1);
  k2_gates<<<dim3(16, 16), 256, 0, stream>>>(x1, h_prev, Wih, Whh, bih, bhh, gates);
  k3_lstm<<<512, 128, 0, stream>>>(gates, c_prev, Wsw, Wsb, o_h, o_c, decf);
  k4_et<<<2048, 256, 0, stream>>>(h_i, bw, decf, cov, Wcw, Vw, e_t);
  k5_softmax_ctx<<<512, 256, 0, stream>>>(e_t, cov, h_i, a_t, o_cov, o_ctx);
  k6_pv1_pgen<<<512, 256, 0, stream>>>(o_h, o_c, o_ctx, emb, x, V1w, V1b, W2w, W2b,
                                       a_t, pv1bf, pgen, attn);
  k7_vocab<<<944, 256, 0, stream>>>(pv1bf, V2w, V2b, outF);
  k8_final<<<512, 1024, 0, stream>>>(pgen, code, attn, outF);
}

// Round 8
// 262.636 us; speedup vs baseline: 1.2236x; 1.0996x over previous
//
#include <hip/hip_runtime.h>
#include <math.h>

// Shapes (fixed by the reference)
#define B_    512
#define T_    512
#define DEC_  128
#define EMB_  512
#define VOC_  30001
#define VEXT_ 30051   // VOC_ + 50 OOV
#define VPAD_ 30080   // 235 * 128 (k7 tile-padded vocab)

typedef float f32x4 __attribute__((ext_vector_type(4)));
typedef short s16x4 __attribute__((ext_vector_type(4)));
typedef short s16x8 __attribute__((ext_vector_type(8)));

#define L2E 1.4426950408889634f

__device__ __forceinline__ float sigmoid_f(float x) {
  float xc = fminf(fmaxf(x, -30.f), 30.f);
  float t = exp2f(xc * L2E);
  return t / (1.f + t);
}
__device__ __forceinline__ float tanh_f(float x) {
  float xc = fminf(fmaxf(x, -15.f), 15.f);
  float t = exp2f(xc * (2.f * L2E));
  return (t - 1.f) / (t + 1.f);
}
// f32 -> bf16 (RNE)
__device__ __forceinline__ short f2bf(float f) {
  unsigned u = __builtin_bit_cast(unsigned, f);
  u += 0x7FFFu + ((u >> 16) & 1u);
  return (short)(u >> 16);
}
__device__ __forceinline__ float bf2f(unsigned short h) {
  return __builtin_bit_cast(float, (unsigned)h << 16);
}
// 128B-aligned bf16 logits base for row b, inside row b's own d_out slot.
__device__ __forceinline__ unsigned short* logit_row(float* outF, int b) {
  size_t byteoff = ((size_t)b * VEXT_ * 4 + 127) & ~(size_t)127;
  return (unsigned short*)((char*)outF + byteoff);
}
// async global -> LDS, 16 bytes per lane (dest = wave-uniform base + lane*16)
__device__ __forceinline__ void gload_lds16(const void* g, void* l) {
  __builtin_amdgcn_global_load_lds(
      (const __attribute__((address_space(1))) void*)g,
      (__attribute__((address_space(3))) void*)l, 16, 0, 0);
}

// ---------------------------------------------------------------------------
// K0: convert Wh_w (128x128 f32) to bf16 MFMA B-fragments, fragment-linear.
// ---------------------------------------------------------------------------
__global__ __launch_bounds__(256) void k0_prep(
    const float* __restrict__ Whw, unsigned short* __restrict__ bw) {
  const int t = threadIdx.x;
#pragma unroll
  for (int i = 0; i < 16; ++i) {
    int p = t + 256 * i;          // (frag, lane) pair
    int f = p >> 6, l = p & 63;
    int nf = f >> 3, kf = f & 7;
    int rowN = nf * 16 + (l & 15);
    int colK = kf * 16 + (l >> 4) * 4;
    f32x4 w = *(const f32x4*)(Whw + rowN * 128 + colK);
    s16x4 bb; bb[0] = f2bf(w[0]); bb[1] = f2bf(w[1]); bb[2] = f2bf(w[2]); bb[3] = f2bf(w[3]);
    *(s16x4*)&bw[p * 4] = bb;
  }
}

// ---------------------------------------------------------------------------
// K0b: V2_w (30001x384 f32) -> bf16 ROW-MAJOR [30080][384], rows >= VOC_ = 0.
// Thread handles 8 consecutive elements (16B store). grid = 5640 x 256.
// ---------------------------------------------------------------------------
__global__ __launch_bounds__(256) void k0b_prepv2h(
    const float* __restrict__ V2w, unsigned short* __restrict__ v2bh) {
  int p = blockIdx.x * 256 + threadIdx.x;   // chunk index, 48 chunks per row
  int row = p / 48;
  int k = (p - row * 48) * 8;
  s16x8 bb;
  if (row < VOC_) {
    const float* src = V2w + (size_t)row * 384 + k;
    f32x4 w0 = *(const f32x4*)src;
    f32x4 w1 = *(const f32x4*)(src + 4);
    bb[0] = f2bf(w0[0]); bb[1] = f2bf(w0[1]); bb[2] = f2bf(w0[2]); bb[3] = f2bf(w0[3]);
    bb[4] = f2bf(w1[0]); bb[5] = f2bf(w1[1]); bb[6] = f2bf(w1[2]); bb[7] = f2bf(w1[3]);
  } else {
    bb = (s16x8){0, 0, 0, 0, 0, 0, 0, 0};
  }
  *(s16x8*)&v2bh[(size_t)p * 8] = bb;
}

// ---------------------------------------------------------------------------
// K1: x1[b,f] = sum_k [emb[x[b]] | ctx_prev][b,k] * W1_w[f,k] + W1_b[f]
// ---------------------------------------------------------------------------
__global__ __launch_bounds__(256) void k1_x1(
    const float* __restrict__ emb, const int* __restrict__ x,
    const float* __restrict__ ctxp, const float* __restrict__ W1w,
    const float* __restrict__ W1b, float* __restrict__ x1) {
  __shared__ float As[32][33];
  __shared__ float Ws[32][33];
  const int tid = threadIdx.x;
  const int f0 = blockIdx.x * 32, b0 = blockIdx.y * 32;
  const int row = tid >> 3, seg = tid & 7;
  const int tx = tid & 15, ty = tid >> 4;
  float a00 = 0.f, a01 = 0.f, a10 = 0.f, a11 = 0.f;
  for (int k0 = 0; k0 < 640; k0 += 32) {
    int k = k0 + seg * 4;
    f32x4 av;
    if (k < 512) {
      int xb = x[b0 + row];
      av = *(const f32x4*)(emb + xb * 512 + k);
    } else {
      av = *(const f32x4*)(ctxp + (b0 + row) * 128 + (k - 512));
    }
    As[row][seg * 4 + 0] = av[0]; As[row][seg * 4 + 1] = av[1];
    As[row][seg * 4 + 2] = av[2]; As[row][seg * 4 + 3] = av[3];
    f32x4 wv = *(const f32x4*)(W1w + (f0 + row) * 640 + k);
    Ws[row][seg * 4 + 0] = wv[0]; Ws[row][seg * 4 + 1] = wv[1];
    Ws[row][seg * 4 + 2] = wv[2]; Ws[row][seg * 4 + 3] = wv[3];
    __syncthreads();
#pragma unroll
    for (int kk = 0; kk < 32; ++kk) {
      float v0 = As[ty * 2][kk], v1 = As[ty * 2 + 1][kk];
      float w0 = Ws[tx * 2][kk], w1 = Ws[tx * 2 + 1][kk];
      a00 += v0 * w0; a01 += v0 * w1; a10 += v1 * w0; a11 += v1 * w1;
    }
    __syncthreads();
  }
  int fo = f0 + tx * 2, bo = b0 + ty * 2;
  x1[bo * 512 + fo]           = a00 + W1b[fo];
  x1[bo * 512 + fo + 1]       = a01 + W1b[fo + 1];
  x1[(bo + 1) * 512 + fo]     = a10 + W1b[fo];
  x1[(bo + 1) * 512 + fo + 1] = a11 + W1b[fo + 1];
}

// ---------------------------------------------------------------------------
// K2: gates[b,j] = sum [x1 | h_prev][b,k] * [W_ih | W_hh][j,k] + b_ih + b_hh
// ---------------------------------------------------------------------------
__global__ __launch_bounds__(256) void k2_gates(
    const float* __restrict__ x1, const float* __restrict__ hprev,
    const float* __restrict__ Wih, const float* __restrict__ Whh,
    const float* __restrict__ bih, const float* __restrict__ bhh,
    float* __restrict__ gates) {
  __shared__ float As[32][33];
  __shared__ float Ws[32][33];
  const int tid = threadIdx.x;
  const int f0 = blockIdx.x * 32, b0 = blockIdx.y * 32;
  const int row = tid >> 3, seg = tid & 7;
  const int tx = tid & 15, ty = tid >> 4;
  float a00 = 0.f, a01 = 0.f, a10 = 0.f, a11 = 0.f;
  for (int k0 = 0; k0 < 640; k0 += 32) {
    int k = k0 + seg * 4;
    f32x4 av, wv;
    if (k < 512) {
      av = *(const f32x4*)(x1 + (b0 + row) * 512 + k);
      wv = *(const f32x4*)(Wih + (f0 + row) * 512 + k);
    } else {
      av = *(const f32x4*)(hprev + (b0 + row) * 128 + (k - 512));
      wv = *(const f32x4*)(Whh + (f0 + row) * 128 + (k - 512));
    }
    As[row][seg * 4 + 0] = av[0]; As[row][seg * 4 + 1] = av[1];
    As[row][seg * 4 + 2] = av[2]; As[row][seg * 4 + 3] = av[3];
    Ws[row][seg * 4 + 0] = wv[0]; Ws[row][seg * 4 + 1] = wv[1];
    Ws[row][seg * 4 + 2] = wv[2]; Ws[row][seg * 4 + 3] = wv[3];
    __syncthreads();
#pragma unroll
    for (int kk = 0; kk < 32; ++kk) {
      float v0 = As[ty * 2][kk], v1 = As[ty * 2 + 1][kk];
      float w0 = Ws[tx * 2][kk], w1 = Ws[tx * 2 + 1][kk];
      a00 += v0 * w0; a01 += v0 * w1; a10 += v1 * w0; a11 += v1 * w1;
    }
    __syncthreads();
  }
  int fo = f0 + tx * 2, bo = b0 + ty * 2;
  gates[bo * 512 + fo]           = a00 + bih[fo] + bhh[fo];
  gates[bo * 512 + fo + 1]       = a01 + bih[fo + 1] + bhh[fo + 1];
  gates[(bo + 1) * 512 + fo]     = a10 + bih[fo] + bhh[fo];
  gates[(bo + 1) * 512 + fo + 1] = a11 + bih[fo + 1] + bhh[fo + 1];
}

// ---------------------------------------------------------------------------
// K3: LSTM cell + dec_f = s_t @ Ws_w^T + Ws_b.  One block per b, 128 threads.
// ---------------------------------------------------------------------------
__global__ __launch_bounds__(128) void k3_lstm(
    const float* __restrict__ gates, const float* __restrict__ cprev,
    const float* __restrict__ Wsw, const float* __restrict__ Wsb,
    float* __restrict__ out_h, float* __restrict__ out_c,
    float* __restrict__ decf) {
  __shared__ float st[256];
  int b = blockIdx.x, d = threadIdx.x;
  const float* g = gates + b * 512;
  float iv = sigmoid_f(g[d]);
  float fv = sigmoid_f(g[128 + d]);
  float gv = tanh_f(g[256 + d]);
  float ov = sigmoid_f(g[384 + d]);
  float c = fv * cprev[b * 128 + d] + iv * gv;
  float h = ov * tanh_f(c);
  out_h[b * 128 + d] = h;
  out_c[b * 128 + d] = c;
  st[d] = h; st[128 + d] = c;
  __syncthreads();
  float acc = Wsb[d];
  const float* wr = Wsw + d * 256;
#pragma unroll 4
  for (int k = 0; k < 256; ++k) acc += st[k] * wr[k];
  decf[b * 128 + d] = acc;
}

// ---------------------------------------------------------------------------
// K4 v2: e_t[b,t] = V_w . tanh(h_i@Wh^T + dec_f[b] + cov[b,t]*Wc)
// grid = B*4 = 2048 blocks (4 waves each), wave owns 32 t x all 128 d.
// ---------------------------------------------------------------------------
__global__ __launch_bounds__(256, 4) void k4_et(
    const float* __restrict__ h_i, const unsigned short* __restrict__ bw,
    const float* __restrict__ decf, const float* __restrict__ cov,
    const float* __restrict__ Wcw, const float* __restrict__ Vw,
    float* __restrict__ e_t) {
  const int b = blockIdx.x >> 2;
  const int q = blockIdx.x & 3;
  const int wv = threadIdx.x >> 6;
  const int lane = threadIdx.x & 63;
  const int lm = lane & 15, lg = lane >> 4;
  const int t0 = q * 128 + wv * 32;

  s16x4 afr[2][8];
#pragma unroll
  for (int mf = 0; mf < 2; ++mf) {
#pragma unroll
    for (int kf = 0; kf < 8; ++kf) {
      const float* p = h_i + (size_t)(b * 512 + t0 + mf * 16 + lm) * 128 + kf * 16 + lg * 4;
      f32x4 v = *(const f32x4*)p;
      s16x4 a; a[0] = f2bf(v[0]); a[1] = f2bf(v[1]); a[2] = f2bf(v[2]); a[3] = f2bf(v[3]);
      afr[mf][kf] = a;
    }
  }
  float dec_v[8], vw_v[8], wc_v[8];
#pragma unroll
  for (int nf = 0; nf < 8; ++nf) {
    dec_v[nf] = decf[b * 128 + nf * 16 + lm];
    vw_v[nf]  = Vw[nf * 16 + lm];
    wc_v[nf]  = Wcw[nf * 16 + lm];
  }
  float cov_v[8];
#pragma unroll
  for (int mf = 0; mf < 2; ++mf)
#pragma unroll
    for (int r = 0; r < 4; ++r)
      cov_v[mf * 4 + r] = cov[b * 512 + t0 + mf * 16 + lg * 4 + r];

  float e_acc[8];
#pragma unroll
  for (int i = 0; i < 8; ++i) e_acc[i] = 0.f;

  const f32x4 zf4 = {0.f, 0.f, 0.f, 0.f};
#pragma unroll
  for (int nf = 0; nf < 8; ++nf) {
    s16x4 bfr[8];
#pragma unroll
    for (int kf = 0; kf < 8; ++kf)
      bfr[kf] = *(const s16x4*)&bw[(((nf * 8 + kf) * 64) + lane) * 4];
    f32x4 acc0 = zf4, acc1 = zf4;
#pragma unroll
    for (int kf = 0; kf < 8; ++kf) {
      acc0 = __builtin_amdgcn_mfma_f32_16x16x16bf16_1k(afr[0][kf], bfr[kf], acc0, 0, 0, 0);
      acc1 = __builtin_amdgcn_mfma_f32_16x16x16bf16_1k(afr[1][kf], bfr[kf], acc1, 0, 0, 0);
    }
#pragma unroll
    for (int r = 0; r < 4; ++r) {
      float v0 = acc0[r] + dec_v[nf] + cov_v[r] * wc_v[nf];
      e_acc[r] += vw_v[nf] * tanh_f(v0);
      float v1 = acc1[r] + dec_v[nf] + cov_v[4 + r] * wc_v[nf];
      e_acc[4 + r] += vw_v[nf] * tanh_f(v1);
    }
  }
#pragma unroll
  for (int i = 0; i < 8; ++i) {
    float v = e_acc[i];
    v += __shfl_xor(v, 1); v += __shfl_xor(v, 2);
    v += __shfl_xor(v, 4); v += __shfl_xor(v, 8);
    e_acc[i] = v;
  }
  if (lm == 0) {
#pragma unroll
    for (int mf = 0; mf < 2; ++mf)
#pragma unroll
      for (int r = 0; r < 4; ++r)
        e_t[b * 512 + t0 + mf * 16 + lg * 4 + r] = e_acc[mf * 4 + r];
  }
}

// ---------------------------------------------------------------------------
// K5: softmax over t, coverage_new, ctx = sum_t a_t * h_i. One block per b.
// ---------------------------------------------------------------------------
__global__ __launch_bounds__(256) void k5_softmax_ctx(
    const float* __restrict__ e_t, const float* __restrict__ cov,
    const float* __restrict__ h_i, float* __restrict__ a_t,
    float* __restrict__ cov_out, float* __restrict__ ctx_out) {
  __shared__ float sm[512];
  __shared__ float red[1024];
  __shared__ float wred[8];
  int b = blockIdx.x, tid = threadIdx.x;
  float e0 = e_t[b * 512 + tid], e1 = e_t[b * 512 + 256 + tid];
  float m = fmaxf(e0, e1);
  for (int off = 32; off; off >>= 1) m = fmaxf(m, __shfl_xor(m, off));
  if ((tid & 63) == 0) wred[tid >> 6] = m;
  __syncthreads();
  m = fmaxf(fmaxf(wred[0], wred[1]), fmaxf(wred[2], wred[3]));
  float x0 = exp2f((e0 - m) * L2E);
  float x1v = exp2f((e1 - m) * L2E);
  float s = x0 + x1v;
  for (int off = 32; off; off >>= 1) s += __shfl_xor(s, off);
  if ((tid & 63) == 0) wred[4 + (tid >> 6)] = s;
  __syncthreads();
  s = wred[4] + wred[5] + wred[6] + wred[7];
  float inv = 1.f / s;
  float a0 = x0 * inv, a1 = x1v * inv;
  a_t[b * 512 + tid] = a0;
  a_t[b * 512 + 256 + tid] = a1;
  cov_out[b * 512 + tid] = cov[b * 512 + tid] + a0;
  cov_out[b * 512 + 256 + tid] = cov[b * 512 + 256 + tid] + a1;
  sm[tid] = a0; sm[256 + tid] = a1;
  __syncthreads();
  int j = tid & 31, tg = tid >> 5;
  const float* hb = h_i + (size_t)b * 512 * 128 + j * 4;
  f32x4 acc = {0.f, 0.f, 0.f, 0.f};
#pragma unroll 8
  for (int t = tg; t < 512; t += 8) {
    float a = sm[t];
    f32x4 hv = *(const f32x4*)(hb + (size_t)t * 128);
    acc += hv * a;
  }
  *(f32x4*)&red[tid * 4] = acc;
  __syncthreads();
  if (tid < 128) {
    float sacc = 0.f;
#pragma unroll
    for (int g = 0; g < 8; ++g) sacc += red[g * 128 + tid];
    ctx_out[b * 128 + tid] = sacc;
  }
}

// ---------------------------------------------------------------------------
// K6: pv1(bf16) = [h|ctx]@V1^T + V1_b ; p_gen ; attn_dist = (1-p_gen)*a_t
// ---------------------------------------------------------------------------
__global__ __launch_bounds__(256) void k6_pv1_pgen(
    const float* __restrict__ out_h, const float* __restrict__ out_c,
    const float* __restrict__ ctx, const float* __restrict__ emb,
    const int* __restrict__ x, const float* __restrict__ V1w,
    const float* __restrict__ V1b, const float* __restrict__ W2w,
    const float* __restrict__ W2b, const float* __restrict__ a_t,
    unsigned short* __restrict__ pv1bf, float* __restrict__ pgen,
    float* __restrict__ attn_out) {
  __shared__ float cat[896];  // [ctx(128) | h(128) | c(128) | xe(512)]
  __shared__ float wr_[4];
  int b = blockIdx.x, tid = threadIdx.x;
  if (tid < 128) {
    cat[tid] = ctx[b * 128 + tid];
    cat[128 + tid] = out_h[b * 128 + tid];
  } else {
    int q = tid - 128;
    cat[256 + q] = out_c[b * 128 + q];
  }
  int xb = x[b];
  for (int k = tid; k < 512; k += 256) cat[384 + k] = emb[xb * 512 + k];
  __syncthreads();
  for (int f = tid; f < 384; f += 256) {
    const float* w = V1w + f * 256;
    float acc = V1b[f];
#pragma unroll 4
    for (int k = 0; k < 256; ++k) {
      float av = (k < 128) ? cat[128 + k] : cat[k - 128];
      acc += av * w[k];
    }
    pv1bf[b * 384 + f] = (unsigned short)f2bf(acc);
  }
  float p = 0.f;
  for (int k = tid; k < 896; k += 256) p += cat[k] * W2w[k];
  for (int off = 32; off; off >>= 1) p += __shfl_xor(p, off);
  if ((tid & 63) == 0) wr_[tid >> 6] = p;
  __syncthreads();
  float pg = sigmoid_f(wr_[0] + wr_[1] + wr_[2] + wr_[3] + W2b[0]);
  if (tid == 0) pgen[b] = pg;
  float om = 1.f - pg;
  attn_out[b * 512 + tid]       = om * a_t[b * 512 + tid];
  attn_out[b * 512 + 256 + tid] = om * a_t[b * 512 + 256 + tid];
}

// ---------------------------------------------------------------------------
// K7 v6 (m97-structure): logits(bf16) = pv1 @ v2bh^T + V2b -> aligned region
// in each d_out row slot. 940 blocks = 235 col-panels x 4 row-panels;
// 128x128 tile, BK=64, 4 waves (64x64 each). A and B staged to LDS via
// global_load_lds width=16 into FRAGMENT-LINEAR layout (lane-linear dest ==
// fragment layout -> conflict-free ds_read_b128, no swizzle needed).
// Epilogue: per-wave LDS transpose -> 128B-full-line bf16 stores (R7-proven).
// ---------------------------------------------------------------------------
__global__ __launch_bounds__(256) void k7_vocab(
    const unsigned short* __restrict__ pv1bf, const unsigned short* __restrict__ v2bh,
    const float* __restrict__ V2b, float* __restrict__ outF) {
  __shared__ char smem[33280];                 // staging 32KB; epilogue 33280B
  unsigned short* Al = (unsigned short*)smem;          // 16 frags x 512 shorts
  unsigned short* Bl = (unsigned short*)(smem + 16384);
  const int bx = blockIdx.x;
  const int rp = bx & 3, cp = bx >> 2;
  const int r0 = rp * 128, c0 = cp * 128;
  const int tid = threadIdx.x;
  const int wv = tid >> 6, lane = tid & 63;
  const int lm = lane & 15, lg = lane >> 4;
  const int rh2 = wv >> 1, ch = wv & 1;

  const f32x4 zf4 = {0.f, 0.f, 0.f, 0.f};
  f32x4 acc[4][4];
#pragma unroll
  for (int m = 0; m < 4; ++m)
#pragma unroll
    for (int nf = 0; nf < 4; ++nf) acc[m][nf] = zf4;

  for (int ks = 0; ks < 6; ++ks) {
    // stage: each wave fills fragments wv*4 .. wv*4+3 of A and B
#pragma unroll
    for (int i = 0; i < 4; ++i) {
      int fi = wv * 4 + i;
      int rt = fi >> 1, kf = fi & 1;
      const unsigned short* sa =
          pv1bf + (r0 + rt * 16 + lm) * 384 + ks * 64 + kf * 32 + lg * 8;
      gload_lds16(sa, &Al[fi * 512 + lane * 8]);
      const unsigned short* sb =
          v2bh + (size_t)(c0 + rt * 16 + lm) * 384 + ks * 64 + kf * 32 + lg * 8;
      gload_lds16(sb, &Bl[fi * 512 + lane * 8]);
    }
    __syncthreads();   // compiler drains vmcnt before s_barrier
#pragma unroll
    for (int kf = 0; kf < 2; ++kf) {
      s16x8 a[4];
#pragma unroll
      for (int m = 0; m < 4; ++m)
        a[m] = *(const s16x8*)&Al[(((rh2 * 4 + m) * 2) + kf) * 512 + lane * 8];
#pragma unroll
      for (int nf = 0; nf < 4; ++nf) {
        s16x8 bfr = *(const s16x8*)&Bl[(((ch * 4 + nf) * 2) + kf) * 512 + lane * 8];
#pragma unroll
        for (int m = 0; m < 4; ++m)
          acc[m][nf] = __builtin_amdgcn_mfma_f32_16x16x32_bf16(a[m], bfr, acc[m][nf], 0, 0, 0);
      }
    }
    __syncthreads();
  }

  // bias (0 for padded cols >= VOC_ -> stores benign zeros k8 ignores)
  const int cw0 = c0 + ch * 64;   // wave's 64-col base (multiple of 64)
  float bias[4];
#pragma unroll
  for (int nf = 0; nf < 4; ++nf) {
    int col = cw0 + nf * 16 + lm;
    bias[nf] = (col < VOC_) ? V2b[col] : 0.f;
  }

  // Epilogue: two passes of 32 rows through wave-private LDS tile (32x65 f32)
  float* T = (float*)smem + wv * 2080;
  const int rq = lane >> 4, cq = lane & 15;
#pragma unroll
  for (int p = 0; p < 2; ++p) {
#pragma unroll
    for (int mm = 0; mm < 2; ++mm) {
      int m = p * 2 + mm;
#pragma unroll
      for (int nf = 0; nf < 4; ++nf)
#pragma unroll
        for (int r = 0; r < 4; ++r)
          T[(mm * 16 + lg * 4 + r) * 65 + nf * 16 + lm] = acc[m][nf][r] + bias[nf];
    }
#pragma unroll
    for (int it = 0; it < 8; ++it) {
      int trow = it * 4 + rq;
      f32x4 vv = *(const f32x4*)&T[trow * 65 + cq * 4];
      s16x4 hb;
      hb[0] = f2bf(vv[0]); hb[1] = f2bf(vv[1]); hb[2] = f2bf(vv[2]); hb[3] = f2bf(vv[3]);
      int orow = r0 + rh2 * 64 + p * 32 + trow;
      unsigned short* dst = logit_row(outF, orow);
      *(s16x4*)&dst[cw0 + cq * 4] = hb;
    }
  }
}

// ---------------------------------------------------------------------------
// K7 fallback (R7 kernel, proven) -- used only if ws can't hold v2bh.
// ---------------------------------------------------------------------------
__global__ __launch_bounds__(256) void k7_vocab_fb(
    const unsigned short* __restrict__ pv1bf, const float* __restrict__ V2w,
    const float* __restrict__ V2b, float* __restrict__ outF) {
  __shared__ float lt[4][32 * 65];
  const int q = blockIdx.x;
  const int nb = ((q >> 4) << 3) + (q & 7);
  const int rh = (q >> 3) & 1;
  if (nb >= 469) return;
  const int v0 = nb * 64;
  const int tid = threadIdx.x;
  const int wv = tid >> 6, lane = tid & 63;
  const int lm = lane & 15, lg = lane >> 4;
  const int r0 = rh * 256 + wv * 64;

  const f32x4 zf4 = {0.f, 0.f, 0.f, 0.f};
  f32x4 acc[4][4];
#pragma unroll
  for (int m = 0; m < 4; ++m)
#pragma unroll
    for (int nf = 0; nf < 4; ++nf) acc[m][nf] = zf4;

  int vrow[4]; bool vok[4];
#pragma unroll
  for (int nf = 0; nf < 4; ++nf) {
    int v = v0 + nf * 16 + lm;
    vok[nf] = (v < VOC_);
    vrow[nf] = vok[nf] ? v : (VOC_ - 1);
  }

#pragma unroll
  for (int kf = 0; kf < 12; ++kf) {
    s16x8 afr[4];
#pragma unroll
    for (int m = 0; m < 4; ++m)
      afr[m] = *(const s16x8*)&pv1bf[(r0 + m * 16 + lm) * 384 + kf * 32 + lg * 8];
    s16x8 bfr[4];
#pragma unroll
    for (int nf = 0; nf < 4; ++nf) {
      const float* p = V2w + (size_t)vrow[nf] * 384 + kf * 32 + lg * 8;
      f32x4 w0 = *(const f32x4*)p;
      f32x4 w1 = *(const f32x4*)(p + 4);
      if (!vok[nf]) { w0 = zf4; w1 = zf4; }
      s16x8 bb;
      bb[0] = f2bf(w0[0]); bb[1] = f2bf(w0[1]); bb[2] = f2bf(w0[2]); bb[3] = f2bf(w0[3]);
      bb[4] = f2bf(w1[0]); bb[5] = f2bf(w1[1]); bb[6] = f2bf(w1[2]); bb[7] = f2bf(w1[3]);
      bfr[nf] = bb;
    }
#pragma unroll
    for (int m = 0; m < 4; ++m)
#pragma unroll
      for (int nf = 0; nf < 4; ++nf)
        acc[m][nf] = __builtin_amdgcn_mfma_f32_16x16x32_bf16(afr[m], bfr[nf], acc[m][nf], 0, 0, 0);
  }

  float bias[4];
#pragma unroll
  for (int nf = 0; nf < 4; ++nf)
    bias[nf] = vok[nf] ? V2b[v0 + nf * 16 + lm] : 0.f;

  float* T = lt[wv];
  const int rq = lane >> 4, cq = lane & 15;
#pragma unroll
  for (int p = 0; p < 2; ++p) {
#pragma unroll
    for (int mm = 0; mm < 2; ++mm) {
      int m = p * 2 + mm;
#pragma unroll
      for (int nf = 0; nf < 4; ++nf)
#pragma unroll
        for (int r = 0; r < 4; ++r)
          T[(mm * 16 + lg * 4 + r) * 65 + nf * 16 + lm] = acc[m][nf][r] + bias[nf];
    }
#pragma unroll
    for (int it = 0; it < 8; ++it) {
      int trow = it * 4 + rq;
      f32x4 vv = *(const f32x4*)&T[trow * 65 + cq * 4];
      s16x4 hb;
      hb[0] = f2bf(vv[0]); hb[1] = f2bf(vv[1]); hb[2] = f2bf(vv[2]); hb[3] = f2bf(vv[3]);
      int orow = r0 + p * 32 + trow;
      unsigned short* dst = logit_row(outF, orow);
      *(s16x4*)&dst[v0 + cq * 4] = hb;
    }
  }
}

// ---------------------------------------------------------------------------
// K8: per-row softmax over bf16 logits (aligned region in d_out row slot),
// scale by p_gen, write f32 final_dist in place, zero 50 OOV cols,
// scatter-add attn_dist with WORKGROUP-scope atomics. One block per b.
// In-place safety: ALL logit reads land in registers before first barrier.
// ---------------------------------------------------------------------------
#define K8_IT 30  // ceil(VOC_/1024)

__global__ __launch_bounds__(1024) void k8_final(
    const float* __restrict__ pgen, const int* __restrict__ code_ext,
    const float* __restrict__ attn, float* __restrict__ outF) {
  __shared__ float lm_[16], ls_[16];
  const int b = blockIdx.x, tid = threadIdx.x;
  float* row = outF + (size_t)b * VEXT_;
  const unsigned short* lrow = logit_row(outF, b);

  float lv[K8_IT];
#pragma unroll
  for (int i = 0; i < K8_IT; ++i) {
    int v = tid + i * 1024;
    lv[i] = (v < VOC_) ? bf2f(lrow[v]) : -3.4e38f;
  }
  float m = lv[0];
#pragma unroll
  for (int i = 1; i < K8_IT; ++i) m = fmaxf(m, lv[i]);
  for (int off = 32; off; off >>= 1) m = fmaxf(m, __shfl_xor(m, off));
  if ((tid & 63) == 0) lm_[tid >> 6] = m;
  __syncthreads();
  float M = lm_[0];
#pragma unroll
  for (int i = 1; i < 16; ++i) M = fmaxf(M, lm_[i]);
  float s = 0.f;
#pragma unroll
  for (int i = 0; i < K8_IT; ++i) {
    lv[i] = exp2f((lv[i] - M) * L2E);
    s += lv[i];
  }
  for (int off = 32; off; off >>= 1) s += __shfl_xor(s, off);
  if ((tid & 63) == 0) ls_[tid >> 6] = s;
  __syncthreads();
  float S = 0.f;
#pragma unroll
  for (int i = 0; i < 16; ++i) S += ls_[i];
  float pm = pgen[b] / S;
#pragma unroll
  for (int i = 0; i < K8_IT; ++i) {
    int v = tid + i * 1024;
    if (v < VOC_) row[v] = pm * lv[i];
  }
  if (tid < 50) row[VOC_ + tid] = 0.f;
  __syncthreads();  // drains vmcnt: all row stores are at the local L2
  if (tid < 512) {
    int idx = code_ext[b * 512 + tid];
    __hip_atomic_fetch_add(&row[idx], attn[b * 512 + tid],
                           __ATOMIC_RELAXED, __HIP_MEMORY_SCOPE_WORKGROUP);
  }
}

// ---------------------------------------------------------------------------
extern "C" void kernel_launch(void* const* d_in, const int* in_sizes, int n_in,
                              void* d_out, int out_size, void* d_ws, size_t ws_size,
                              hipStream_t stream) {
  (void)in_sizes; (void)n_in; (void)out_size;
  const float* h_i    = (const float*)d_in[0];
  const float* h_prev = (const float*)d_in[1];
  const float* c_prev = (const float*)d_in[2];
  const float* ctxp   = (const float*)d_in[3];
  const float* cov    = (const float*)d_in[4];
  const float* emb    = (const float*)d_in[5];
  const float* Wih    = (const float*)d_in[6];
  const float* Whh    = (const float*)d_in[7];
  const float* bih    = (const float*)d_in[8];
  const float* bhh    = (const float*)d_in[9];
  const float* W1w    = (const float*)d_in[10];
  const float* W1b    = (const float*)d_in[11];
  const float* W2w    = (const float*)d_in[12];
  const float* W2b    = (const float*)d_in[13];
  const float* V1w    = (const float*)d_in[14];
  const float* V1b    = (const float*)d_in[15];
  const float* V2w    = (const float*)d_in[16];
  const float* V2b    = (const float*)d_in[17];
  const float* Whw    = (const float*)d_in[18];
  const float* Wsw    = (const float*)d_in[19];
  const float* Wsb    = (const float*)d_in[20];
  const float* Wcw    = (const float*)d_in[21];
  const float* Vw     = (const float*)d_in[22];
  const int*   x      = (const int*)d_in[23];
  const int*   code   = (const int*)d_in[24];

  float* ws    = (float*)d_ws;
  float* x1    = ws;                 // 262144
  float* gates = ws + 262144;        // 262144
  float* decf  = ws + 524288;        // 65536
  float* e_t   = ws + 589824;        // 262144
  float* a_t   = ws + 851968;        // 262144
  unsigned short* pv1bf = (unsigned short*)(ws + 1114112);  // 196608 shorts
  float* pgen  = ws + 1212416;       // 512
  // bw (bf16 Wh_w fragments) aliases the a_t region: bw lives k0..k4; a_t is
  // first written in k5. No overlap in time.
  unsigned short* bw = (unsigned short*)(ws + 851968);
  // v2bh: bf16 V2_w row-major [30080][384] = 11,550,720 shorts
  unsigned short* v2bh = (unsigned short*)(ws + 1212928);
  const size_t WS_NEEDED = (size_t)(1212928 + 5775360) * 4;  // 27,953,152 B
  const bool use_v6 = (ws_size >= WS_NEEDED);

  float* outF  = (float*)d_out;                    // final_dist 512 x 30051
  float* attn  = outF + (size_t)512 * VEXT_;       // 262144
  float* o_h   = attn + 262144;                    // 65536
  float* o_c   = o_h + 65536;                      // 65536
  float* o_cov = o_c + 65536;                      // 262144
  float* o_ctx = o_cov + 262144;                   // 65536

  k0_prep<<<1, 256, 0, stream>>>(Whw, bw);
  if (use_v6) k0b_prepv2h<<<5640, 256, 0, stream>>>(V2w, v2bh);
  k1_x1<<<dim3(16, 16), 256, 0, stream>>>(emb, x, ctxp, W1w, W1b, x1);
  k2_gates<<<dim3(16, 16), 256, 0, stream>>>(x1, h_prev, Wih, Whh, bih, bhh, gates);
  k3_lstm<<<512, 128, 0, stream>>>(gates, c_prev, Wsw, Wsb, o_h, o_c, decf);
  k4_et<<<2048, 256, 0, stream>>>(h_i, bw, decf, cov, Wcw, Vw, e_t);
  k5_softmax_ctx<<<512, 256, 0, stream>>>(e_t, cov, h_i, a_t, o_cov, o_ctx);
  k6_pv1_pgen<<<512, 256, 0, stream>>>(o_h, o_c, o_ctx, emb, x, V1w, V1b, W2w, W2b,
                                       a_t, pv1bf, pgen, attn);
  if (use_v6)
    k7_vocab<<<940, 256, 0, stream>>>(pv1bf, v2bh, V2b, outF);
  else
    k7_vocab_fb<<<944, 256, 0, stream>>>(pv1bf, V2w, V2b, outF);
  k8_final<<<512, 1024, 0, stream>>>(pgen, code, attn, outF);
}

// Round 9
// 250.978 us; speedup vs baseline: 1.2805x; 1.0465x over previous
//
#include <hip/hip_runtime.h>
#include <math.h>

// Shapes (fixed by the reference)
#define B_    512
#define T_    512
#define DEC_  128
#define EMB_  512
#define VOC_  30001
#define VEXT_ 30051   // VOC_ + 50 OOV
#define VPAD_ 30080   // 235 * 128 (k7 tile-padded vocab)

typedef float f32x4 __attribute__((ext_vector_type(4)));
typedef short s16x4 __attribute__((ext_vector_type(4)));
typedef short s16x8 __attribute__((ext_vector_type(8)));

#define L2E 1.4426950408889634f

__device__ __forceinline__ float sigmoid_f(float x) {
  float xc = fminf(fmaxf(x, -30.f), 30.f);
  float t = exp2f(xc * L2E);
  return t / (1.f + t);
}
__device__ __forceinline__ float tanh_f(float x) {
  float xc = fminf(fmaxf(x, -15.f), 15.f);
  float t = exp2f(xc * (2.f * L2E));
  return (t - 1.f) / (t + 1.f);
}
// f32 -> bf16 (RNE)
__device__ __forceinline__ short f2bf(float f) {
  unsigned u = __builtin_bit_cast(unsigned, f);
  u += 0x7FFFu + ((u >> 16) & 1u);
  return (short)(u >> 16);
}
__device__ __forceinline__ float bf2f(unsigned short h) {
  return __builtin_bit_cast(float, (unsigned)h << 16);
}
// 128B-aligned bf16 logits base for row b, inside row b's own d_out slot.
__device__ __forceinline__ unsigned short* logit_row(float* outF, int b) {
  size_t byteoff = ((size_t)b * VEXT_ * 4 + 127) & ~(size_t)127;
  return (unsigned short*)((char*)outF + byteoff);
}
// async global -> LDS, 16 bytes per lane (dest = wave-uniform base + lane*16)
__device__ __forceinline__ void gload_lds16(const void* g, void* l) {
  __builtin_amdgcn_global_load_lds(
      (const __attribute__((address_space(1))) void*)g,
      (__attribute__((address_space(3))) void*)l, 16, 0, 0);
}

// ---------------------------------------------------------------------------
// K0: convert Wh_w (128x128 f32) to bf16 MFMA B-fragments, fragment-linear.
// ---------------------------------------------------------------------------
__global__ __launch_bounds__(256) void k0_prep(
    const float* __restrict__ Whw, unsigned short* __restrict__ bw) {
  const int t = threadIdx.x;
#pragma unroll
  for (int i = 0; i < 16; ++i) {
    int p = t + 256 * i;          // (frag, lane) pair
    int f = p >> 6, l = p & 63;
    int nf = f >> 3, kf = f & 7;
    int rowN = nf * 16 + (l & 15);
    int colK = kf * 16 + (l >> 4) * 4;
    f32x4 w = *(const f32x4*)(Whw + rowN * 128 + colK);
    s16x4 bb; bb[0] = f2bf(w[0]); bb[1] = f2bf(w[1]); bb[2] = f2bf(w[2]); bb[3] = f2bf(w[3]);
    *(s16x4*)&bw[p * 4] = bb;
  }
}

// ---------------------------------------------------------------------------
// K0b: V2_w (30001x384 f32) -> bf16 ROW-MAJOR [30080][384], rows >= VOC_ = 0.
// ---------------------------------------------------------------------------
__global__ __launch_bounds__(256) void k0b_prepv2h(
    const float* __restrict__ V2w, unsigned short* __restrict__ v2bh) {
  int p = blockIdx.x * 256 + threadIdx.x;   // chunk index, 48 chunks per row
  int row = p / 48;
  int k = (p - row * 48) * 8;
  s16x8 bb;
  if (row < VOC_) {
    const float* src = V2w + (size_t)row * 384 + k;
    f32x4 w0 = *(const f32x4*)src;
    f32x4 w1 = *(const f32x4*)(src + 4);
    bb[0] = f2bf(w0[0]); bb[1] = f2bf(w0[1]); bb[2] = f2bf(w0[2]); bb[3] = f2bf(w0[3]);
    bb[4] = f2bf(w1[0]); bb[5] = f2bf(w1[1]); bb[6] = f2bf(w1[2]); bb[7] = f2bf(w1[3]);
  } else {
    bb = (s16x8){0, 0, 0, 0, 0, 0, 0, 0};
  }
  *(s16x8*)&v2bh[(size_t)p * 8] = bb;
}

// ---------------------------------------------------------------------------
// K1: x1[b,f] = sum_k [emb[x[b]] | ctx_prev][b,k] * W1_w[f,k] + W1_b[f]
// ---------------------------------------------------------------------------
__global__ __launch_bounds__(256) void k1_x1(
    const float* __restrict__ emb, const int* __restrict__ x,
    const float* __restrict__ ctxp, const float* __restrict__ W1w,
    const float* __restrict__ W1b, float* __restrict__ x1) {
  __shared__ float As[32][33];
  __shared__ float Ws[32][33];
  const int tid = threadIdx.x;
  const int f0 = blockIdx.x * 32, b0 = blockIdx.y * 32;
  const int row = tid >> 3, seg = tid & 7;
  const int tx = tid & 15, ty = tid >> 4;
  float a00 = 0.f, a01 = 0.f, a10 = 0.f, a11 = 0.f;
  for (int k0 = 0; k0 < 640; k0 += 32) {
    int k = k0 + seg * 4;
    f32x4 av;
    if (k < 512) {
      int xb = x[b0 + row];
      av = *(const f32x4*)(emb + xb * 512 + k);
    } else {
      av = *(const f32x4*)(ctxp + (b0 + row) * 128 + (k - 512));
    }
    As[row][seg * 4 + 0] = av[0]; As[row][seg * 4 + 1] = av[1];
    As[row][seg * 4 + 2] = av[2]; As[row][seg * 4 + 3] = av[3];
    f32x4 wv = *(const f32x4*)(W1w + (f0 + row) * 640 + k);
    Ws[row][seg * 4 + 0] = wv[0]; Ws[row][seg * 4 + 1] = wv[1];
    Ws[row][seg * 4 + 2] = wv[2]; Ws[row][seg * 4 + 3] = wv[3];
    __syncthreads();
#pragma unroll
    for (int kk = 0; kk < 32; ++kk) {
      float v0 = As[ty * 2][kk], v1 = As[ty * 2 + 1][kk];
      float w0 = Ws[tx * 2][kk], w1 = Ws[tx * 2 + 1][kk];
      a00 += v0 * w0; a01 += v0 * w1; a10 += v1 * w0; a11 += v1 * w1;
    }
    __syncthreads();
  }
  int fo = f0 + tx * 2, bo = b0 + ty * 2;
  x1[bo * 512 + fo]           = a00 + W1b[fo];
  x1[bo * 512 + fo + 1]       = a01 + W1b[fo + 1];
  x1[(bo + 1) * 512 + fo]     = a10 + W1b[fo];
  x1[(bo + 1) * 512 + fo + 1] = a11 + W1b[fo + 1];
}

// ---------------------------------------------------------------------------
// K2: gates[b,j] = sum [x1 | h_prev][b,k] * [W_ih | W_hh][j,k] + b_ih + b_hh
// ---------------------------------------------------------------------------
__global__ __launch_bounds__(256) void k2_gates(
    const float* __restrict__ x1, const float* __restrict__ hprev,
    const float* __restrict__ Wih, const float* __restrict__ Whh,
    const float* __restrict__ bih, const float* __restrict__ bhh,
    float* __restrict__ gates) {
  __shared__ float As[32][33];
  __shared__ float Ws[32][33];
  const int tid = threadIdx.x;
  const int f0 = blockIdx.x * 32, b0 = blockIdx.y * 32;
  const int row = tid >> 3, seg = tid & 7;
  const int tx = tid & 15, ty = tid >> 4;
  float a00 = 0.f, a01 = 0.f, a10 = 0.f, a11 = 0.f;
  for (int k0 = 0; k0 < 640; k0 += 32) {
    int k = k0 + seg * 4;
    f32x4 av, wv;
    if (k < 512) {
      av = *(const f32x4*)(x1 + (b0 + row) * 512 + k);
      wv = *(const f32x4*)(Wih + (f0 + row) * 512 + k);
    } else {
      av = *(const f32x4*)(hprev + (b0 + row) * 128 + (k - 512));
      wv = *(const f32x4*)(Whh + (f0 + row) * 128 + (k - 512));
    }
    As[row][seg * 4 + 0] = av[0]; As[row][seg * 4 + 1] = av[1];
    As[row][seg * 4 + 2] = av[2]; As[row][seg * 4 + 3] = av[3];
    Ws[row][seg * 4 + 0] = wv[0]; Ws[row][seg * 4 + 1] = wv[1];
    Ws[row][seg * 4 + 2] = wv[2]; Ws[row][seg * 4 + 3] = wv[3];
    __syncthreads();
#pragma unroll
    for (int kk = 0; kk < 32; ++kk) {
      float v0 = As[ty * 2][kk], v1 = As[ty * 2 + 1][kk];
      float w0 = Ws[tx * 2][kk], w1 = Ws[tx * 2 + 1][kk];
      a00 += v0 * w0; a01 += v0 * w1; a10 += v1 * w0; a11 += v1 * w1;
    }
    __syncthreads();
  }
  int fo = f0 + tx * 2, bo = b0 + ty * 2;
  gates[bo * 512 + fo]           = a00 + bih[fo] + bhh[fo];
  gates[bo * 512 + fo + 1]       = a01 + bih[fo + 1] + bhh[fo + 1];
  gates[(bo + 1) * 512 + fo]     = a10 + bih[fo] + bhh[fo];
  gates[(bo + 1) * 512 + fo + 1] = a11 + bih[fo + 1] + bhh[fo + 1];
}

// ---------------------------------------------------------------------------
// K3: LSTM cell + dec_f = s_t @ Ws_w^T + Ws_b.  One block per b, 128 threads.
// ---------------------------------------------------------------------------
__global__ __launch_bounds__(128) void k3_lstm(
    const float* __restrict__ gates, const float* __restrict__ cprev,
    const float* __restrict__ Wsw, const float* __restrict__ Wsb,
    float* __restrict__ out_h, float* __restrict__ out_c,
    float* __restrict__ decf) {
  __shared__ float st[256];
  int b = blockIdx.x, d = threadIdx.x;
  const float* g = gates + b * 512;
  float iv = sigmoid_f(g[d]);
  float fv = sigmoid_f(g[128 + d]);
  float gv = tanh_f(g[256 + d]);
  float ov = sigmoid_f(g[384 + d]);
  float c = fv * cprev[b * 128 + d] + iv * gv;
  float h = ov * tanh_f(c);
  out_h[b * 128 + d] = h;
  out_c[b * 128 + d] = c;
  st[d] = h; st[128 + d] = c;
  __syncthreads();
  float acc = Wsb[d];
  const float* wr = Wsw + d * 256;
#pragma unroll 4
  for (int k = 0; k < 256; ++k) acc += st[k] * wr[k];
  decf[b * 128 + d] = acc;
}

// ---------------------------------------------------------------------------
// K4 v3: e_t[b,t] = V_w . tanh(h_i@Wh^T + dec_f[b] + cov[b,t]*Wc)
// Round-9 change: bw (32 KB frag-linear Wh_w) staged to LDS once per block
// via global_load_lds; inner-loop B reads become conflict-free ds_read_b64
// (2 lanes/bank = free). Dropped the min-waves-4 launch bound that capped
// VGPR at 64 and serialized the B loads in the MFMA chain (R8 post-mortem).
// grid = B*4 = 2048 blocks (4 waves each), wave owns 32 t x all 128 d.
// ---------------------------------------------------------------------------
__global__ __launch_bounds__(256) void k4_et(
    const float* __restrict__ h_i, const unsigned short* __restrict__ bw,
    const float* __restrict__ decf, const float* __restrict__ cov,
    const float* __restrict__ Wcw, const float* __restrict__ Vw,
    float* __restrict__ e_t) {
  __shared__ unsigned short bwl[16384];   // 32 KB fragment-linear copy
  const int b = blockIdx.x >> 2;
  const int q = blockIdx.x & 3;
  const int tid = threadIdx.x;
  const int wv = tid >> 6;
  const int lane = tid & 63;
  const int lm = lane & 15, lg = lane >> 4;
  const int t0 = q * 128 + wv * 32;

  // stage bw -> LDS (8 x 16B per thread, lane-linear dest == layout)
#pragma unroll
  for (int i = 0; i < 8; ++i)
    gload_lds16(&bw[(tid + i * 256) * 8], &bwl[(tid + i * 256) * 8]);

  // A fragments (h_i stream, 16 x 16B per lane issued up front)
  s16x4 afr[2][8];
#pragma unroll
  for (int mf = 0; mf < 2; ++mf) {
#pragma unroll
    for (int kf = 0; kf < 8; ++kf) {
      const float* p = h_i + (size_t)(b * 512 + t0 + mf * 16 + lm) * 128 + kf * 16 + lg * 4;
      f32x4 v = *(const f32x4*)p;
      s16x4 a; a[0] = f2bf(v[0]); a[1] = f2bf(v[1]); a[2] = f2bf(v[2]); a[3] = f2bf(v[3]);
      afr[mf][kf] = a;
    }
  }
  float dec_v[8], vw_v[8], wc_v[8];
#pragma unroll
  for (int nf = 0; nf < 8; ++nf) {
    dec_v[nf] = decf[b * 128 + nf * 16 + lm];
    vw_v[nf]  = Vw[nf * 16 + lm];
    wc_v[nf]  = Wcw[nf * 16 + lm];
  }
  float cov_v[8];
#pragma unroll
  for (int mf = 0; mf < 2; ++mf)
#pragma unroll
    for (int r = 0; r < 4; ++r)
      cov_v[mf * 4 + r] = cov[b * 512 + t0 + mf * 16 + lg * 4 + r];

  __syncthreads();   // drains vmcnt incl. global_load_lds before use

  float e_acc[8];
#pragma unroll
  for (int i = 0; i < 8; ++i) e_acc[i] = 0.f;

  const f32x4 zf4 = {0.f, 0.f, 0.f, 0.f};
#pragma unroll
  for (int nf = 0; nf < 8; ++nf) {
    s16x4 bfr[8];
#pragma unroll
    for (int kf = 0; kf < 8; ++kf)
      bfr[kf] = *(const s16x4*)&bwl[(((nf * 8 + kf) * 64) + lane) * 4];
    f32x4 acc0 = zf4, acc1 = zf4;
#pragma unroll
    for (int kf = 0; kf < 8; ++kf) {
      acc0 = __builtin_amdgcn_mfma_f32_16x16x16bf16_1k(afr[0][kf], bfr[kf], acc0, 0, 0, 0);
      acc1 = __builtin_amdgcn_mfma_f32_16x16x16bf16_1k(afr[1][kf], bfr[kf], acc1, 0, 0, 0);
    }
#pragma unroll
    for (int r = 0; r < 4; ++r) {
      float v0 = acc0[r] + dec_v[nf] + cov_v[r] * wc_v[nf];
      e_acc[r] += vw_v[nf] * tanh_f(v0);
      float v1 = acc1[r] + dec_v[nf] + cov_v[4 + r] * wc_v[nf];
      e_acc[4 + r] += vw_v[nf] * tanh_f(v1);
    }
  }
#pragma unroll
  for (int i = 0; i < 8; ++i) {
    float v = e_acc[i];
    v += __shfl_xor(v, 1); v += __shfl_xor(v, 2);
    v += __shfl_xor(v, 4); v += __shfl_xor(v, 8);
    e_acc[i] = v;
  }
  if (lm == 0) {
#pragma unroll
    for (int mf = 0; mf < 2; ++mf)
#pragma unroll
      for (int r = 0; r < 4; ++r)
        e_t[b * 512 + t0 + mf * 16 + lg * 4 + r] = e_acc[mf * 4 + r];
  }
}

// ---------------------------------------------------------------------------
// K5: softmax over t, coverage_new, ctx = sum_t a_t * h_i. One block per b.
// ---------------------------------------------------------------------------
__global__ __launch_bounds__(256) void k5_softmax_ctx(
    const float* __restrict__ e_t, const float* __restrict__ cov,
    const float* __restrict__ h_i, float* __restrict__ a_t,
    float* __restrict__ cov_out, float* __restrict__ ctx_out) {
  __shared__ float sm[512];
  __shared__ float red[1024];
  __shared__ float wred[8];
  int b = blockIdx.x, tid = threadIdx.x;
  float e0 = e_t[b * 512 + tid], e1 = e_t[b * 512 + 256 + tid];
  float m = fmaxf(e0, e1);
  for (int off = 32; off; off >>= 1) m = fmaxf(m, __shfl_xor(m, off));
  if ((tid & 63) == 0) wred[tid >> 6] = m;
  __syncthreads();
  m = fmaxf(fmaxf(wred[0], wred[1]), fmaxf(wred[2], wred[3]));
  float x0 = exp2f((e0 - m) * L2E);
  float x1v = exp2f((e1 - m) * L2E);
  float s = x0 + x1v;
  for (int off = 32; off; off >>= 1) s += __shfl_xor(s, off);
  if ((tid & 63) == 0) wred[4 + (tid >> 6)] = s;
  __syncthreads();
  s = wred[4] + wred[5] + wred[6] + wred[7];
  float inv = 1.f / s;
  float a0 = x0 * inv, a1 = x1v * inv;
  a_t[b * 512 + tid] = a0;
  a_t[b * 512 + 256 + tid] = a1;
  cov_out[b * 512 + tid] = cov[b * 512 + tid] + a0;
  cov_out[b * 512 + 256 + tid] = cov[b * 512 + 256 + tid] + a1;
  sm[tid] = a0; sm[256 + tid] = a1;
  __syncthreads();
  int j = tid & 31, tg = tid >> 5;
  const float* hb = h_i + (size_t)b * 512 * 128 + j * 4;
  f32x4 acc = {0.f, 0.f, 0.f, 0.f};
#pragma unroll 8
  for (int t = tg; t < 512; t += 8) {
    float a = sm[t];
    f32x4 hv = *(const f32x4*)(hb + (size_t)t * 128);
    acc += hv * a;
  }
  *(f32x4*)&red[tid * 4] = acc;
  __syncthreads();
  if (tid < 128) {
    float sacc = 0.f;
#pragma unroll
    for (int g = 0; g < 8; ++g) sacc += red[g * 128 + tid];
    ctx_out[b * 128 + tid] = sacc;
  }
}

// ---------------------------------------------------------------------------
// K6: pv1(bf16) = [h|ctx]@V1^T + V1_b ; p_gen ; attn_dist = (1-p_gen)*a_t
// ---------------------------------------------------------------------------
__global__ __launch_bounds__(256) void k6_pv1_pgen(
    const float* __restrict__ out_h, const float* __restrict__ out_c,
    const float* __restrict__ ctx, const float* __restrict__ emb,
    const int* __restrict__ x, const float* __restrict__ V1w,
    const float* __restrict__ V1b, const float* __restrict__ W2w,
    const float* __restrict__ W2b, const float* __restrict__ a_t,
    unsigned short* __restrict__ pv1bf, float* __restrict__ pgen,
    float* __restrict__ attn_out) {
  __shared__ float cat[896];  // [ctx(128) | h(128) | c(128) | xe(512)]
  __shared__ float wr_[4];
  int b = blockIdx.x, tid = threadIdx.x;
  if (tid < 128) {
    cat[tid] = ctx[b * 128 + tid];
    cat[128 + tid] = out_h[b * 128 + tid];
  } else {
    int q = tid - 128;
    cat[256 + q] = out_c[b * 128 + q];
  }
  int xb = x[b];
  for (int k = tid; k < 512; k += 256) cat[384 + k] = emb[xb * 512 + k];
  __syncthreads();
  for (int f = tid; f < 384; f += 256) {
    const float* w = V1w + f * 256;
    float acc = V1b[f];
#pragma unroll 4
    for (int k = 0; k < 256; ++k) {
      float av = (k < 128) ? cat[128 + k] : cat[k - 128];
      acc += av * w[k];
    }
    pv1bf[b * 384 + f] = (unsigned short)f2bf(acc);
  }
  float p = 0.f;
  for (int k = tid; k < 896; k += 256) p += cat[k] * W2w[k];
  for (int off = 32; off; off >>= 1) p += __shfl_xor(p, off);
  if ((tid & 63) == 0) wr_[tid >> 6] = p;
  __syncthreads();
  float pg = sigmoid_f(wr_[0] + wr_[1] + wr_[2] + wr_[3] + W2b[0]);
  if (tid == 0) pgen[b] = pg;
  float om = 1.f - pg;
  attn_out[b * 512 + tid]       = om * a_t[b * 512 + tid];
  attn_out[b * 512 + 256 + tid] = om * a_t[b * 512 + 256 + tid];
}

// ---------------------------------------------------------------------------
// K7 v6 (m97-structure): logits(bf16) = pv1 @ v2bh^T + V2b -> aligned region
// in each d_out row slot. 940 blocks = 235 col-panels x 4 row-panels;
// 128x128 tile, BK=64, 4 waves (64x64 each). A and B staged to LDS via
// global_load_lds width=16 into FRAGMENT-LINEAR layout.
// ---------------------------------------------------------------------------
__global__ __launch_bounds__(256) void k7_vocab(
    const unsigned short* __restrict__ pv1bf, const unsigned short* __restrict__ v2bh,
    const float* __restrict__ V2b, float* __restrict__ outF) {
  __shared__ char smem[33280];                 // staging 32KB; epilogue 33280B
  unsigned short* Al = (unsigned short*)smem;          // 16 frags x 512 shorts
  unsigned short* Bl = (unsigned short*)(smem + 16384);
  const int bx = blockIdx.x;
  const int rp = bx & 3, cp = bx >> 2;
  const int r0 = rp * 128, c0 = cp * 128;
  const int tid = threadIdx.x;
  const int wv = tid >> 6, lane = tid & 63;
  const int lm = lane & 15, lg = lane >> 4;
  const int rh2 = wv >> 1, ch = wv & 1;

  const f32x4 zf4 = {0.f, 0.f, 0.f, 0.f};
  f32x4 acc[4][4];
#pragma unroll
  for (int m = 0; m < 4; ++m)
#pragma unroll
    for (int nf = 0; nf < 4; ++nf) acc[m][nf] = zf4;

  for (int ks = 0; ks < 6; ++ks) {
    // stage: each wave fills fragments wv*4 .. wv*4+3 of A and B
#pragma unroll
    for (int i = 0; i < 4; ++i) {
      int fi = wv * 4 + i;
      int rt = fi >> 1, kf = fi & 1;
      const unsigned short* sa =
          pv1bf + (r0 + rt * 16 + lm) * 384 + ks * 64 + kf * 32 + lg * 8;
      gload_lds16(sa, &Al[fi * 512 + lane * 8]);
      const unsigned short* sb =
          v2bh + (size_t)(c0 + rt * 16 + lm) * 384 + ks * 64 + kf * 32 + lg * 8;
      gload_lds16(sb, &Bl[fi * 512 + lane * 8]);
    }
    __syncthreads();   // compiler drains vmcnt before s_barrier
#pragma unroll
    for (int kf = 0; kf < 2; ++kf) {
      s16x8 a[4];
#pragma unroll
      for (int m = 0; m < 4; ++m)
        a[m] = *(const s16x8*)&Al[(((rh2 * 4 + m) * 2) + kf) * 512 + lane * 8];
#pragma unroll
      for (int nf = 0; nf < 4; ++nf) {
        s16x8 bfr = *(const s16x8*)&Bl[(((ch * 4 + nf) * 2) + kf) * 512 + lane * 8];
#pragma unroll
        for (int m = 0; m < 4; ++m)
          acc[m][nf] = __builtin_amdgcn_mfma_f32_16x16x32_bf16(a[m], bfr, acc[m][nf], 0, 0, 0);
      }
    }
    __syncthreads();
  }

  // bias (0 for padded cols >= VOC_ -> stores benign zeros k8 ignores)
  const int cw0 = c0 + ch * 64;   // wave's 64-col base (multiple of 64)
  float bias[4];
#pragma unroll
  for (int nf = 0; nf < 4; ++nf) {
    int col = cw0 + nf * 16 + lm;
    bias[nf] = (col < VOC_) ? V2b[col] : 0.f;
  }

  // Epilogue: two passes of 32 rows through wave-private LDS tile (32x65 f32)
  float* T = (float*)smem + wv * 2080;
  const int rq = lane >> 4, cq = lane & 15;
#pragma unroll
  for (int p = 0; p < 2; ++p) {
#pragma unroll
    for (int mm = 0; mm < 2; ++mm) {
      int m = p * 2 + mm;
#pragma unroll
      for (int nf = 0; nf < 4; ++nf)
#pragma unroll
        for (int r = 0; r < 4; ++r)
          T[(mm * 16 + lg * 4 + r) * 65 + nf * 16 + lm] = acc[m][nf][r] + bias[nf];
    }
#pragma unroll
    for (int it = 0; it < 8; ++it) {
      int trow = it * 4 + rq;
      f32x4 vv = *(const f32x4*)&T[trow * 65 + cq * 4];
      s16x4 hb;
      hb[0] = f2bf(vv[0]); hb[1] = f2bf(vv[1]); hb[2] = f2bf(vv[2]); hb[3] = f2bf(vv[3]);
      int orow = r0 + rh2 * 64 + p * 32 + trow;
      unsigned short* dst = logit_row(outF, orow);
      *(s16x4*)&dst[cw0 + cq * 4] = hb;
    }
  }
}

// ---------------------------------------------------------------------------
// K7 fallback (R7 kernel, proven) -- used only if ws can't hold v2bh.
// ---------------------------------------------------------------------------
__global__ __launch_bounds__(256) void k7_vocab_fb(
    const unsigned short* __restrict__ pv1bf, const float* __restrict__ V2w,
    const float* __restrict__ V2b, float* __restrict__ outF) {
  __shared__ float lt[4][32 * 65];
  const int q = blockIdx.x;
  const int nb = ((q >> 4) << 3) + (q & 7);
  const int rh = (q >> 3) & 1;
  if (nb >= 469) return;
  const int v0 = nb * 64;
  const int tid = threadIdx.x;
  const int wv = tid >> 6, lane = tid & 63;
  const int lm = lane & 15, lg = lane >> 4;
  const int r0 = rh * 256 + wv * 64;

  const f32x4 zf4 = {0.f, 0.f, 0.f, 0.f};
  f32x4 acc[4][4];
#pragma unroll
  for (int m = 0; m < 4; ++m)
#pragma unroll
    for (int nf = 0; nf < 4; ++nf) acc[m][nf] = zf4;

  int vrow[4]; bool vok[4];
#pragma unroll
  for (int nf = 0; nf < 4; ++nf) {
    int v = v0 + nf * 16 + lm;
    vok[nf] = (v < VOC_);
    vrow[nf] = vok[nf] ? v : (VOC_ - 1);
  }

#pragma unroll
  for (int kf = 0; kf < 12; ++kf) {
    s16x8 afr[4];
#pragma unroll
    for (int m = 0; m < 4; ++m)
      afr[m] = *(const s16x8*)&pv1bf[(r0 + m * 16 + lm) * 384 + kf * 32 + lg * 8];
    s16x8 bfr[4];
#pragma unroll
    for (int nf = 0; nf < 4; ++nf) {
      const float* p = V2w + (size_t)vrow[nf] * 384 + kf * 32 + lg * 8;
      f32x4 w0 = *(const f32x4*)p;
      f32x4 w1 = *(const f32x4*)(p + 4);
      if (!vok[nf]) { w0 = zf4; w1 = zf4; }
      s16x8 bb;
      bb[0] = f2bf(w0[0]); bb[1] = f2bf(w0[1]); bb[2] = f2bf(w0[2]); bb[3] = f2bf(w0[3]);
      bb[4] = f2bf(w1[0]); bb[5] = f2bf(w1[1]); bb[6] = f2bf(w1[2]); bb[7] = f2bf(w1[3]);
      bfr[nf] = bb;
    }
#pragma unroll
    for (int m = 0; m < 4; ++m)
#pragma unroll
      for (int nf = 0; nf < 4; ++nf)
        acc[m][nf] = __builtin_amdgcn_mfma_f32_16x16x32_bf16(afr[m], bfr[nf], acc[m][nf], 0, 0, 0);
  }

  float bias[4];
#pragma unroll
  for (int nf = 0; nf < 4; ++nf)
    bias[nf] = vok[nf] ? V2b[v0 + nf * 16 + lm] : 0.f;

  float* T = lt[wv];
  const int rq = lane >> 4, cq = lane & 15;
#pragma unroll
  for (int p = 0; p < 2; ++p) {
#pragma unroll
    for (int mm = 0; mm < 2; ++mm) {
      int m = p * 2 + mm;
#pragma unroll
      for (int nf = 0; nf < 4; ++nf)
#pragma unroll
        for (int r = 0; r < 4; ++r)
          T[(mm * 16 + lg * 4 + r) * 65 + nf * 16 + lm] = acc[m][nf][r] + bias[nf];
    }
#pragma unroll
    for (int it = 0; it < 8; ++it) {
      int trow = it * 4 + rq;
      f32x4 vv = *(const f32x4*)&T[trow * 65 + cq * 4];
      s16x4 hb;
      hb[0] = f2bf(vv[0]); hb[1] = f2bf(vv[1]); hb[2] = f2bf(vv[2]); hb[3] = f2bf(vv[3]);
      int orow = r0 + p * 32 + trow;
      unsigned short* dst = logit_row(outF, orow);
      *(s16x4*)&dst[v0 + cq * 4] = hb;
    }
  }
}

// ---------------------------------------------------------------------------
// K8: per-row softmax over bf16 logits (aligned region in d_out row slot),
// scale by p_gen, write f32 final_dist in place, zero 50 OOV cols,
// scatter-add attn_dist with WORKGROUP-scope atomics. One block per b.
// In-place safety: ALL logit reads land in registers before first barrier.
// ---------------------------------------------------------------------------
#define K8_IT 30  // ceil(VOC_/1024)

__global__ __launch_bounds__(1024) void k8_final(
    const float* __restrict__ pgen, const int* __restrict__ code_ext,
    const float* __restrict__ attn, float* __restrict__ outF) {
  __shared__ float lm_[16], ls_[16];
  const int b = blockIdx.x, tid = threadIdx.x;
  float* row = outF + (size_t)b * VEXT_;
  const unsigned short* lrow = logit_row(outF, b);

  float lv[K8_IT];
#pragma unroll
  for (int i = 0; i < K8_IT; ++i) {
    int v = tid + i * 1024;
    lv[i] = (v < VOC_) ? bf2f(lrow[v]) : -3.4e38f;
  }
  float m = lv[0];
#pragma unroll
  for (int i = 1; i < K8_IT; ++i) m = fmaxf(m, lv[i]);
  for (int off = 32; off; off >>= 1) m = fmaxf(m, __shfl_xor(m, off));
  if ((tid & 63) == 0) lm_[tid >> 6] = m;
  __syncthreads();
  float M = lm_[0];
#pragma unroll
  for (int i = 1; i < 16; ++i) M = fmaxf(M, lm_[i]);
  float s = 0.f;
#pragma unroll
  for (int i = 0; i < K8_IT; ++i) {
    lv[i] = exp2f((lv[i] - M) * L2E);
    s += lv[i];
  }
  for (int off = 32; off; off >>= 1) s += __shfl_xor(s, off);
  if ((tid & 63) == 0) ls_[tid >> 6] = s;
  __syncthreads();
  float S = 0.f;
#pragma unroll
  for (int i = 0; i < 16; ++i) S += ls_[i];
  float pm = pgen[b] / S;
#pragma unroll
  for (int i = 0; i < K8_IT; ++i) {
    int v = tid + i * 1024;
    if (v < VOC_) row[v] = pm * lv[i];
  }
  if (tid < 50) row[VOC_ + tid] = 0.f;
  __syncthreads();  // drains vmcnt: all row stores are at the local L2
  if (tid < 512) {
    int idx = code_ext[b * 512 + tid];
    __hip_atomic_fetch_add(&row[idx], attn[b * 512 + tid],
                           __ATOMIC_RELAXED, __HIP_MEMORY_SCOPE_WORKGROUP);
  }
}

// ---------------------------------------------------------------------------
extern "C" void kernel_launch(void* const* d_in, const int* in_sizes, int n_in,
                              void* d_out, int out_size, void* d_ws, size_t ws_size,
                              hipStream_t stream) {
  (void)in_sizes; (void)n_in; (void)out_size;
  const float* h_i    = (const float*)d_in[0];
  const float* h_prev = (const float*)d_in[1];
  const float* c_prev = (const float*)d_in[2];
  const float* ctxp   = (const float*)d_in[3];
  const float* cov    = (const float*)d_in[4];
  const float* emb    = (const float*)d_in[5];
  const float* Wih    = (const float*)d_in[6];
  const float* Whh    = (const float*)d_in[7];
  const float* bih    = (const float*)d_in[8];
  const float* bhh    = (const float*)d_in[9];
  const float* W1w    = (const float*)d_in[10];
  const float* W1b    = (const float*)d_in[11];
  const float* W2w    = (const float*)d_in[12];
  const float* W2b    = (const float*)d_in[13];
  const float* V1w    = (const float*)d_in[14];
  const float* V1b    = (const float*)d_in[15];
  const float* V2w    = (const float*)d_in[16];
  const float* V2b    = (const float*)d_in[17];
  const float* Whw    = (const float*)d_in[18];
  const float* Wsw    = (const float*)d_in[19];
  const float* Wsb    = (const float*)d_in[20];
  const float* Wcw    = (const float*)d_in[21];
  const float* Vw     = (const float*)d_in[22];
  const int*   x      = (const int*)d_in[23];
  const int*   code   = (const int*)d_in[24];

  float* ws    = (float*)d_ws;
  float* x1    = ws;                 // 262144
  float* gates = ws + 262144;        // 262144
  float* decf  = ws + 524288;        // 65536
  float* e_t   = ws + 589824;        // 262144
  float* a_t   = ws + 851968;        // 262144
  unsigned short* pv1bf = (unsigned short*)(ws + 1114112);  // 196608 shorts
  float* pgen  = ws + 1212416;       // 512
  // bw (bf16 Wh_w fragments) aliases the a_t region: bw lives k0..k4; a_t is
  // first written in k5. No overlap in time.
  unsigned short* bw = (unsigned short*)(ws + 851968);
  // v2bh: bf16 V2_w row-major [30080][384] = 11,550,720 shorts
  unsigned short* v2bh = (unsigned short*)(ws + 1212928);
  const size_t WS_NEEDED = (size_t)(1212928 + 5775360) * 4;  // 27,953,152 B
  const bool use_v6 = (ws_size >= WS_NEEDED);

  float* outF  = (float*)d_out;                    // final_dist 512 x 30051
  float* attn  = outF + (size_t)512 * VEXT_;       // 262144
  float* o_h   = attn + 262144;                    // 65536
  float* o_c   = o_h + 65536;                      // 65536
  float* o_cov = o_c + 65536;                      // 262144
  float* o_ctx = o_cov + 262144;                   // 65536

  k0_prep<<<1, 256, 0, stream>>>(Whw, bw);
  if (use_v6) k0b_prepv2h<<<5640, 256, 0, stream>>>(V2w, v2bh);
  k1_x1<<<dim3(16, 16), 256, 0, stream>>>(emb, x, ctxp, W1w, W1b, x1);
  k2_gates<<<dim3(16, 16), 256, 0, stream>>>(x1, h_prev, Wih, Whh, bih, bhh, gates);
  k3_lstm<<<512, 128, 0, stream>>>(gates, c_prev, Wsw, Wsb, o_h, o_c, decf);
  k4_et<<<2048, 256, 0, stream>>>(h_i, bw, decf, cov, Wcw, Vw, e_t);
  k5_softmax_ctx<<<512, 256, 0, stream>>>(e_t, cov, h_i, a_t, o_cov, o_ctx);
  k6_pv1_pgen<<<512, 256, 0, stream>>>(o_h, o_c, o_ctx, emb, x, V1w, V1b, W2w, W2b,
                                       a_t, pv1bf, pgen, attn);
  if (use_v6)
    k7_vocab<<<940, 256, 0, stream>>>(pv1bf, v2bh, V2b, outF);
  else
    k7_vocab_fb<<<944, 256, 0, stream>>>(pv1bf, V2w, V2b, outF);
  k8_final<<<512, 1024, 0, stream>>>(pgen, code, attn, outF);
}

// Round 10
// 243.675 us; speedup vs baseline: 1.3189x; 1.0300x over previous
//
#include <hip/hip_runtime.h>
#include <math.h>

// Shapes (fixed by the reference)
#define B_    512
#define T_    512
#define DEC_  128
#define EMB_  512
#define VOC_  30001
#define VEXT_ 30051   // VOC_ + 50 OOV

typedef float f32x4 __attribute__((ext_vector_type(4)));
typedef short s16x4 __attribute__((ext_vector_type(4)));
typedef short s16x8 __attribute__((ext_vector_type(8)));

#define L2E 1.4426950408889634f

// fast sigmoid/tanh: exp2 + hw rcp (1 ulp) -- thresholds are bf16-scale
__device__ __forceinline__ float sigmoid_f(float x) {
  float xc = fminf(fmaxf(x, -30.f), 30.f);
  return __builtin_amdgcn_rcpf(1.f + exp2f(-xc * L2E));
}
__device__ __forceinline__ float tanh_f(float x) {
  float xc = fminf(fmaxf(x, -15.f), 15.f);
  float t = exp2f(xc * (2.f * L2E));
  return 1.f - 2.f * __builtin_amdgcn_rcpf(t + 1.f);
}
// f32 -> bf16 (RNE)
__device__ __forceinline__ short f2bf(float f) {
  unsigned u = __builtin_bit_cast(unsigned, f);
  u += 0x7FFFu + ((u >> 16) & 1u);
  return (short)(u >> 16);
}
__device__ __forceinline__ float bf2f(unsigned short h) {
  return __builtin_bit_cast(float, (unsigned)h << 16);
}
// 128B-aligned bf16 logits base for row b, inside row b's own d_out slot.
__device__ __forceinline__ unsigned short* logit_row(float* outF, int b) {
  size_t byteoff = ((size_t)b * VEXT_ * 4 + 127) & ~(size_t)127;
  return (unsigned short*)((char*)outF + byteoff);
}
// async global -> LDS, 16 bytes per lane (dest = wave-uniform base + lane*16)
__device__ __forceinline__ void gload_lds16(const void* g, void* l) {
  __builtin_amdgcn_global_load_lds(
      (const __attribute__((address_space(1))) void*)g,
      (__attribute__((address_space(3))) void*)l, 16, 0, 0);
}

// ---------------------------------------------------------------------------
// K0 (K=32 layout): Wh_w (128x128 f32) -> bf16 B-fragments, fragment-linear:
// bw[((nf*4+kf)*64 + lane)*8 + e] = Whw[nf*16 + (lane&15)][kf*32 + (lane>>4)*8 + e]
// ---------------------------------------------------------------------------
__global__ __launch_bounds__(256) void k0_prep32(
    const float* __restrict__ Whw, unsigned short* __restrict__ bw) {
  const int t = threadIdx.x;
#pragma unroll
  for (int i = 0; i < 8; ++i) {
    int p = t + 256 * i;          // 0..2047 (frag, lane)
    int f = p >> 6, l = p & 63;
    int nf = f >> 2, kf = f & 3;
    int row = nf * 16 + (l & 15);
    int col = kf * 32 + (l >> 4) * 8;
    const float* src = Whw + row * 128 + col;
    f32x4 w0 = *(const f32x4*)src;
    f32x4 w1 = *(const f32x4*)(src + 4);
    s16x8 bb;
    bb[0] = f2bf(w0[0]); bb[1] = f2bf(w0[1]); bb[2] = f2bf(w0[2]); bb[3] = f2bf(w0[3]);
    bb[4] = f2bf(w1[0]); bb[5] = f2bf(w1[1]); bb[6] = f2bf(w1[2]); bb[7] = f2bf(w1[3]);
    *(s16x8*)&bw[p * 8] = bb;
  }
}

// ---------------------------------------------------------------------------
// K0b: V2_w (30001x384 f32) -> bf16 ROW-MAJOR [30080][384], rows >= VOC_ = 0.
// ---------------------------------------------------------------------------
__global__ __launch_bounds__(256) void k0b_prepv2h(
    const float* __restrict__ V2w, unsigned short* __restrict__ v2bh) {
  int p = blockIdx.x * 256 + threadIdx.x;   // chunk index, 48 chunks per row
  int row = p / 48;
  int k = (p - row * 48) * 8;
  s16x8 bb;
  if (row < VOC_) {
    const float* src = V2w + (size_t)row * 384 + k;
    f32x4 w0 = *(const f32x4*)src;
    f32x4 w1 = *(const f32x4*)(src + 4);
    bb[0] = f2bf(w0[0]); bb[1] = f2bf(w0[1]); bb[2] = f2bf(w0[2]); bb[3] = f2bf(w0[3]);
    bb[4] = f2bf(w1[0]); bb[5] = f2bf(w1[1]); bb[6] = f2bf(w1[2]); bb[7] = f2bf(w1[3]);
  } else {
    bb = (s16x8){0, 0, 0, 0, 0, 0, 0, 0};
  }
  *(s16x8*)&v2bh[(size_t)p * 8] = bb;
}

// ---------------------------------------------------------------------------
// K1: x1[b,f] = sum_k [emb[x[b]] | ctx_prev][b,k] * W1_w[f,k] + W1_b[f]
// ---------------------------------------------------------------------------
__global__ __launch_bounds__(256) void k1_x1(
    const float* __restrict__ emb, const int* __restrict__ x,
    const float* __restrict__ ctxp, const float* __restrict__ W1w,
    const float* __restrict__ W1b, float* __restrict__ x1) {
  __shared__ float As[32][33];
  __shared__ float Ws[32][33];
  const int tid = threadIdx.x;
  const int f0 = blockIdx.x * 32, b0 = blockIdx.y * 32;
  const int row = tid >> 3, seg = tid & 7;
  const int tx = tid & 15, ty = tid >> 4;
  float a00 = 0.f, a01 = 0.f, a10 = 0.f, a11 = 0.f;
  for (int k0 = 0; k0 < 640; k0 += 32) {
    int k = k0 + seg * 4;
    f32x4 av;
    if (k < 512) {
      int xb = x[b0 + row];
      av = *(const f32x4*)(emb + xb * 512 + k);
    } else {
      av = *(const f32x4*)(ctxp + (b0 + row) * 128 + (k - 512));
    }
    As[row][seg * 4 + 0] = av[0]; As[row][seg * 4 + 1] = av[1];
    As[row][seg * 4 + 2] = av[2]; As[row][seg * 4 + 3] = av[3];
    f32x4 wv = *(const f32x4*)(W1w + (f0 + row) * 640 + k);
    Ws[row][seg * 4 + 0] = wv[0]; Ws[row][seg * 4 + 1] = wv[1];
    Ws[row][seg * 4 + 2] = wv[2]; Ws[row][seg * 4 + 3] = wv[3];
    __syncthreads();
#pragma unroll
    for (int kk = 0; kk < 32; ++kk) {
      float v0 = As[ty * 2][kk], v1 = As[ty * 2 + 1][kk];
      float w0 = Ws[tx * 2][kk], w1 = Ws[tx * 2 + 1][kk];
      a00 += v0 * w0; a01 += v0 * w1; a10 += v1 * w0; a11 += v1 * w1;
    }
    __syncthreads();
  }
  int fo = f0 + tx * 2, bo = b0 + ty * 2;
  x1[bo * 512 + fo]           = a00 + W1b[fo];
  x1[bo * 512 + fo + 1]       = a01 + W1b[fo + 1];
  x1[(bo + 1) * 512 + fo]     = a10 + W1b[fo];
  x1[(bo + 1) * 512 + fo + 1] = a11 + W1b[fo + 1];
}

// ---------------------------------------------------------------------------
// K2: gates[b,j] = sum [x1 | h_prev][b,k] * [W_ih | W_hh][j,k] + b_ih + b_hh
// ---------------------------------------------------------------------------
__global__ __launch_bounds__(256) void k2_gates(
    const float* __restrict__ x1, const float* __restrict__ hprev,
    const float* __restrict__ Wih, const float* __restrict__ Whh,
    const float* __restrict__ bih, const float* __restrict__ bhh,
    float* __restrict__ gates) {
  __shared__ float As[32][33];
  __shared__ float Ws[32][33];
  const int tid = threadIdx.x;
  const int f0 = blockIdx.x * 32, b0 = blockIdx.y * 32;
  const int row = tid >> 3, seg = tid & 7;
  const int tx = tid & 15, ty = tid >> 4;
  float a00 = 0.f, a01 = 0.f, a10 = 0.f, a11 = 0.f;
  for (int k0 = 0; k0 < 640; k0 += 32) {
    int k = k0 + seg * 4;
    f32x4 av, wv;
    if (k < 512) {
      av = *(const f32x4*)(x1 + (b0 + row) * 512 + k);
      wv = *(const f32x4*)(Wih + (f0 + row) * 512 + k);
    } else {
      av = *(const f32x4*)(hprev + (b0 + row) * 128 + (k - 512));
      wv = *(const f32x4*)(Whh + (f0 + row) * 128 + (k - 512));
    }
    As[row][seg * 4 + 0] = av[0]; As[row][seg * 4 + 1] = av[1];
    As[row][seg * 4 + 2] = av[2]; As[row][seg * 4 + 3] = av[3];
    Ws[row][seg * 4 + 0] = wv[0]; Ws[row][seg * 4 + 1] = wv[1];
    Ws[row][seg * 4 + 2] = wv[2]; Ws[row][seg * 4 + 3] = wv[3];
    __syncthreads();
#pragma unroll
    for (int kk = 0; kk < 32; ++kk) {
      float v0 = As[ty * 2][kk], v1 = As[ty * 2 + 1][kk];
      float w0 = Ws[tx * 2][kk], w1 = Ws[tx * 2 + 1][kk];
      a00 += v0 * w0; a01 += v0 * w1; a10 += v1 * w0; a11 += v1 * w1;
    }
    __syncthreads();
  }
  int fo = f0 + tx * 2, bo = b0 + ty * 2;
  gates[bo * 512 + fo]           = a00 + bih[fo] + bhh[fo];
  gates[bo * 512 + fo + 1]       = a01 + bih[fo + 1] + bhh[fo + 1];
  gates[(bo + 1) * 512 + fo]     = a10 + bih[fo] + bhh[fo];
  gates[(bo + 1) * 512 + fo + 1] = a11 + bih[fo + 1] + bhh[fo + 1];
}

// ---------------------------------------------------------------------------
// K3: LSTM cell + dec_f = s_t @ Ws_w^T + Ws_b.  One block per b, 128 threads.
// ---------------------------------------------------------------------------
__global__ __launch_bounds__(128) void k3_lstm(
    const float* __restrict__ gates, const float* __restrict__ cprev,
    const float* __restrict__ Wsw, const float* __restrict__ Wsb,
    float* __restrict__ out_h, float* __restrict__ out_c,
    float* __restrict__ decf) {
  __shared__ float st[256];
  int b = blockIdx.x, d = threadIdx.x;
  const float* g = gates + b * 512;
  float iv = sigmoid_f(g[d]);
  float fv = sigmoid_f(g[128 + d]);
  float gv = tanh_f(g[256 + d]);
  float ov = sigmoid_f(g[384 + d]);
  float c = fv * cprev[b * 128 + d] + iv * gv;
  float h = ov * tanh_f(c);
  out_h[b * 128 + d] = h;
  out_c[b * 128 + d] = c;
  st[d] = h; st[128 + d] = c;
  __syncthreads();
  float acc = Wsb[d];
  const float* wr = Wsw + d * 256;
#pragma unroll 4
  for (int k = 0; k < 256; ++k) acc += st[k] * wr[k];
  decf[b * 128 + d] = acc;
}

// ---------------------------------------------------------------------------
// K45 (fused k4+k5): per block = one b (512 thr, 8 waves, wave owns 64 t).
//  1. Wh frags (32 KB) -> LDS via global_load_lds (k7-proven).
//  2. e_t per wave: K=32 MFMA (h_i first read, HBM/L3) + fast tanh.
//  3. block softmax in LDS (NO e_t global round-trip), a_t + cov_out writes.
//  4. ctx: second h_i read (block just streamed its 256 KB -> L2/L3-hot),
//     k5-style f32x4 with 16-way t-split + LDS reduce.
// ---------------------------------------------------------------------------
__global__ __launch_bounds__(512) void k45_attn(
    const float* __restrict__ h_i, const unsigned short* __restrict__ bw,
    const float* __restrict__ decf, const float* __restrict__ cov,
    const float* __restrict__ Wcw, const float* __restrict__ Vw,
    float* __restrict__ a_t, float* __restrict__ cov_out,
    float* __restrict__ ctx_out) {
  __shared__ unsigned short whl[16384];   // 32 KB frag-linear Wh
  __shared__ float sm[512];
  __shared__ float red[16][128];
  __shared__ float wred[8];
  const int b = blockIdx.x;
  const int tid = threadIdx.x;
  const int wv = tid >> 6, lane = tid & 63;
  const int lm = lane & 15, lg = lane >> 4;
  const int t0w = wv * 64;

  // stage Wh fragments (4 x 16B per thread, lane-linear dest == layout)
#pragma unroll
  for (int i = 0; i < 4; ++i)
    gload_lds16(&bw[(tid + i * 512) * 8], &whl[(tid + i * 512) * 8]);

  float dec_v[8], vw_v[8], wc_v[8];
#pragma unroll
  for (int nf = 0; nf < 8; ++nf) {
    dec_v[nf] = decf[b * 128 + nf * 16 + lm];
    vw_v[nf]  = Vw[nf * 16 + lm];
    wc_v[nf]  = Wcw[nf * 16 + lm];
  }
  __syncthreads();   // drains vmcnt incl. global_load_lds

  const f32x4 zf4 = {0.f, 0.f, 0.f, 0.f};
#pragma unroll
  for (int half = 0; half < 2; ++half) {
    // A fragments for 2 m-tiles (32 x 16B global loads per lane, independent)
    s16x8 afr[2][4];
#pragma unroll
    for (int mm = 0; mm < 2; ++mm) {
      int t = t0w + (half * 2 + mm) * 16 + lm;
#pragma unroll
      for (int kf = 0; kf < 4; ++kf) {
        const float* p = h_i + ((size_t)(b * 512 + t)) * 128 + kf * 32 + lg * 8;
        f32x4 v0 = *(const f32x4*)p;
        f32x4 v1 = *(const f32x4*)(p + 4);
        s16x8 a;
        a[0] = f2bf(v0[0]); a[1] = f2bf(v0[1]); a[2] = f2bf(v0[2]); a[3] = f2bf(v0[3]);
        a[4] = f2bf(v1[0]); a[5] = f2bf(v1[1]); a[6] = f2bf(v1[2]); a[7] = f2bf(v1[3]);
        afr[mm][kf] = a;
      }
    }
    float cov_v[8];
#pragma unroll
    for (int mm = 0; mm < 2; ++mm)
#pragma unroll
      for (int r = 0; r < 4; ++r)
        cov_v[mm * 4 + r] = cov[b * 512 + t0w + (half * 2 + mm) * 16 + lg * 4 + r];

    float e_acc[8];
#pragma unroll
    for (int i = 0; i < 8; ++i) e_acc[i] = 0.f;

#pragma unroll
    for (int nf = 0; nf < 8; ++nf) {
      s16x8 bfr[4];
#pragma unroll
      for (int kf = 0; kf < 4; ++kf)
        bfr[kf] = *(const s16x8*)&whl[((nf * 4 + kf) * 64 + lane) * 8];
      f32x4 acc0 = zf4, acc1 = zf4;
#pragma unroll
      for (int kf = 0; kf < 4; ++kf) {
        acc0 = __builtin_amdgcn_mfma_f32_16x16x32_bf16(afr[0][kf], bfr[kf], acc0, 0, 0, 0);
        acc1 = __builtin_amdgcn_mfma_f32_16x16x32_bf16(afr[1][kf], bfr[kf], acc1, 0, 0, 0);
      }
#pragma unroll
      for (int r = 0; r < 4; ++r) {
        float v0 = acc0[r] + dec_v[nf] + cov_v[r] * wc_v[nf];
        e_acc[r] += vw_v[nf] * tanh_f(v0);
        float v1 = acc1[r] + dec_v[nf] + cov_v[4 + r] * wc_v[nf];
        e_acc[4 + r] += vw_v[nf] * tanh_f(v1);
      }
    }
    // reduce over lm (16 lanes), write raw e to LDS
#pragma unroll
    for (int i = 0; i < 8; ++i) {
      float v = e_acc[i];
      v += __shfl_xor(v, 1); v += __shfl_xor(v, 2);
      v += __shfl_xor(v, 4); v += __shfl_xor(v, 8);
      e_acc[i] = v;
    }
    if (lm == 0) {
#pragma unroll
      for (int mm = 0; mm < 2; ++mm)
#pragma unroll
        for (int r = 0; r < 4; ++r)
          sm[t0w + (half * 2 + mm) * 16 + lg * 4 + r] = e_acc[mm * 4 + r];
    }
  }
  __syncthreads();

  // block softmax over sm[0..511]
  float e = sm[tid];
  float m = e;
  for (int off = 32; off; off >>= 1) m = fmaxf(m, __shfl_xor(m, off));
  if (lane == 0) wred[wv] = m;
  __syncthreads();
  float M = wred[0];
#pragma unroll
  for (int i = 1; i < 8; ++i) M = fmaxf(M, wred[i]);
  float ex = exp2f((e - M) * L2E);
  float s = ex;
  for (int off = 32; off; off >>= 1) s += __shfl_xor(s, off);
  __syncthreads();   // everyone has read wred (max) before overwrite
  if (lane == 0) wred[wv] = s;
  __syncthreads();
  float S = 0.f;
#pragma unroll
  for (int i = 0; i < 8; ++i) S += wred[i];
  float a = ex * __builtin_amdgcn_rcpf(S);
  a_t[b * 512 + tid] = a;
  cov_out[b * 512 + tid] = cov[b * 512 + tid] + a;
  sm[tid] = a;
  __syncthreads();

  // ctx = sum_t a[t] * h_i[b,t,:]  (second read, L2/L3-hot)
  int j = tid & 31, tg = tid >> 5;
  const float* hb = h_i + (size_t)b * 65536 + j * 4;
  f32x4 acc = zf4;
#pragma unroll 8
  for (int t = tg; t < 512; t += 16) {
    float av = sm[t];
    f32x4 hv = *(const f32x4*)(hb + (size_t)t * 128);
    acc += hv * av;
  }
  *(f32x4*)&red[tg][j * 4] = acc;
  __syncthreads();
  if (tid < 128) {
    float sa = 0.f;
#pragma unroll
    for (int g = 0; g < 16; ++g) sa += red[g][tid];
    ctx_out[b * 128 + tid] = sa;
  }
}

// ---------------------------------------------------------------------------
// K6: pv1(bf16) = [h|ctx]@V1^T + V1_b ; p_gen ; attn_dist = (1-p_gen)*a_t
// ---------------------------------------------------------------------------
__global__ __launch_bounds__(256) void k6_pv1_pgen(
    const float* __restrict__ out_h, const float* __restrict__ out_c,
    const float* __restrict__ ctx, const float* __restrict__ emb,
    const int* __restrict__ x, const float* __restrict__ V1w,
    const float* __restrict__ V1b, const float* __restrict__ W2w,
    const float* __restrict__ W2b, const float* __restrict__ a_t,
    unsigned short* __restrict__ pv1bf, float* __restrict__ pgen,
    float* __restrict__ attn_out) {
  __shared__ float cat[896];  // [ctx(128) | h(128) | c(128) | xe(512)]
  __shared__ float wr_[4];
  int b = blockIdx.x, tid = threadIdx.x;
  if (tid < 128) {
    cat[tid] = ctx[b * 128 + tid];
    cat[128 + tid] = out_h[b * 128 + tid];
  } else {
    int q = tid - 128;
    cat[256 + q] = out_c[b * 128 + q];
  }
  int xb = x[b];
  for (int k = tid; k < 512; k += 256) cat[384 + k] = emb[xb * 512 + k];
  __syncthreads();
  for (int f = tid; f < 384; f += 256) {
    const float* w = V1w + f * 256;
    float acc = V1b[f];
#pragma unroll 4
    for (int k = 0; k < 256; ++k) {
      float av = (k < 128) ? cat[128 + k] : cat[k - 128];
      acc += av * w[k];
    }
    pv1bf[b * 384 + f] = (unsigned short)f2bf(acc);
  }
  float p = 0.f;
  for (int k = tid; k < 896; k += 256) p += cat[k] * W2w[k];
  for (int off = 32; off; off >>= 1) p += __shfl_xor(p, off);
  if ((tid & 63) == 0) wr_[tid >> 6] = p;
  __syncthreads();
  float pg = sigmoid_f(wr_[0] + wr_[1] + wr_[2] + wr_[3] + W2b[0]);
  if (tid == 0) pgen[b] = pg;
  float om = 1.f - pg;
  attn_out[b * 512 + tid]       = om * a_t[b * 512 + tid];
  attn_out[b * 512 + 256 + tid] = om * a_t[b * 512 + 256 + tid];
}

// ---------------------------------------------------------------------------
// K7 v6 (m97-structure): logits(bf16) = pv1 @ v2bh^T + V2b -> aligned region
// in each d_out row slot. 940 blocks, 128x128 tile, BK=64, 4 waves.
// ---------------------------------------------------------------------------
__global__ __launch_bounds__(256) void k7_vocab(
    const unsigned short* __restrict__ pv1bf, const unsigned short* __restrict__ v2bh,
    const float* __restrict__ V2b, float* __restrict__ outF) {
  __shared__ char smem[33280];                 // staging 32KB; epilogue 33280B
  unsigned short* Al = (unsigned short*)smem;          // 16 frags x 512 shorts
  unsigned short* Bl = (unsigned short*)(smem + 16384);
  const int bx = blockIdx.x;
  const int rp = bx & 3, cp = bx >> 2;
  const int r0 = rp * 128, c0 = cp * 128;
  const int tid = threadIdx.x;
  const int wv = tid >> 6, lane = tid & 63;
  const int lm = lane & 15, lg = lane >> 4;
  const int rh2 = wv >> 1, ch = wv & 1;

  const f32x4 zf4 = {0.f, 0.f, 0.f, 0.f};
  f32x4 acc[4][4];
#pragma unroll
  for (int m = 0; m < 4; ++m)
#pragma unroll
    for (int nf = 0; nf < 4; ++nf) acc[m][nf] = zf4;

  for (int ks = 0; ks < 6; ++ks) {
#pragma unroll
    for (int i = 0; i < 4; ++i) {
      int fi = wv * 4 + i;
      int rt = fi >> 1, kf = fi & 1;
      const unsigned short* sa =
          pv1bf + (r0 + rt * 16 + lm) * 384 + ks * 64 + kf * 32 + lg * 8;
      gload_lds16(sa, &Al[fi * 512 + lane * 8]);
      const unsigned short* sb =
          v2bh + (size_t)(c0 + rt * 16 + lm) * 384 + ks * 64 + kf * 32 + lg * 8;
      gload_lds16(sb, &Bl[fi * 512 + lane * 8]);
    }
    __syncthreads();   // compiler drains vmcnt before s_barrier
#pragma unroll
    for (int kf = 0; kf < 2; ++kf) {
      s16x8 a[4];
#pragma unroll
      for (int m = 0; m < 4; ++m)
        a[m] = *(const s16x8*)&Al[(((rh2 * 4 + m) * 2) + kf) * 512 + lane * 8];
#pragma unroll
      for (int nf = 0; nf < 4; ++nf) {
        s16x8 bfr = *(const s16x8*)&Bl[(((ch * 4 + nf) * 2) + kf) * 512 + lane * 8];
#pragma unroll
        for (int m = 0; m < 4; ++m)
          acc[m][nf] = __builtin_amdgcn_mfma_f32_16x16x32_bf16(a[m], bfr, acc[m][nf], 0, 0, 0);
      }
    }
    __syncthreads();
  }

  const int cw0 = c0 + ch * 64;
  float bias[4];
#pragma unroll
  for (int nf = 0; nf < 4; ++nf) {
    int col = cw0 + nf * 16 + lm;
    bias[nf] = (col < VOC_) ? V2b[col] : 0.f;
  }

  float* T = (float*)smem + wv * 2080;
  const int rq = lane >> 4, cq = lane & 15;
#pragma unroll
  for (int p = 0; p < 2; ++p) {
#pragma unroll
    for (int mm = 0; mm < 2; ++mm) {
      int m = p * 2 + mm;
#pragma unroll
      for (int nf = 0; nf < 4; ++nf)
#pragma unroll
        for (int r = 0; r < 4; ++r)
          T[(mm * 16 + lg * 4 + r) * 65 + nf * 16 + lm] = acc[m][nf][r] + bias[nf];
    }
#pragma unroll
    for (int it = 0; it < 8; ++it) {
      int trow = it * 4 + rq;
      f32x4 vv = *(const f32x4*)&T[trow * 65 + cq * 4];
      s16x4 hb;
      hb[0] = f2bf(vv[0]); hb[1] = f2bf(vv[1]); hb[2] = f2bf(vv[2]); hb[3] = f2bf(vv[3]);
      int orow = r0 + rh2 * 64 + p * 32 + trow;
      unsigned short* dst = logit_row(outF, orow);
      *(s16x4*)&dst[cw0 + cq * 4] = hb;
    }
  }
}

// ---------------------------------------------------------------------------
// K7 fallback (R7 kernel, proven) -- used only if ws can't hold v2bh.
// ---------------------------------------------------------------------------
__global__ __launch_bounds__(256) void k7_vocab_fb(
    const unsigned short* __restrict__ pv1bf, const float* __restrict__ V2w,
    const float* __restrict__ V2b, float* __restrict__ outF) {
  __shared__ float lt[4][32 * 65];
  const int q = blockIdx.x;
  const int nb = ((q >> 4) << 3) + (q & 7);
  const int rh = (q >> 3) & 1;
  if (nb >= 469) return;
  const int v0 = nb * 64;
  const int tid = threadIdx.x;
  const int wv = tid >> 6, lane = tid & 63;
  const int lm = lane & 15, lg = lane >> 4;
  const int r0 = rh * 256 + wv * 64;

  const f32x4 zf4 = {0.f, 0.f, 0.f, 0.f};
  f32x4 acc[4][4];
#pragma unroll
  for (int m = 0; m < 4; ++m)
#pragma unroll
    for (int nf = 0; nf < 4; ++nf) acc[m][nf] = zf4;

  int vrow[4]; bool vok[4];
#pragma unroll
  for (int nf = 0; nf < 4; ++nf) {
    int v = v0 + nf * 16 + lm;
    vok[nf] = (v < VOC_);
    vrow[nf] = vok[nf] ? v : (VOC_ - 1);
  }

#pragma unroll
  for (int kf = 0; kf < 12; ++kf) {
    s16x8 afr[4];
#pragma unroll
    for (int m = 0; m < 4; ++m)
      afr[m] = *(const s16x8*)&pv1bf[(r0 + m * 16 + lm) * 384 + kf * 32 + lg * 8];
    s16x8 bfr[4];
#pragma unroll
    for (int nf = 0; nf < 4; ++nf) {
      const float* p = V2w + (size_t)vrow[nf] * 384 + kf * 32 + lg * 8;
      f32x4 w0 = *(const f32x4*)p;
      f32x4 w1 = *(const f32x4*)(p + 4);
      if (!vok[nf]) { w0 = zf4; w1 = zf4; }
      s16x8 bb;
      bb[0] = f2bf(w0[0]); bb[1] = f2bf(w0[1]); bb[2] = f2bf(w0[2]); bb[3] = f2bf(w0[3]);
      bb[4] = f2bf(w1[0]); bb[5] = f2bf(w1[1]); bb[6] = f2bf(w1[2]); bb[7] = f2bf(w1[3]);
      bfr[nf] = bb;
    }
#pragma unroll
    for (int m = 0; m < 4; ++m)
#pragma unroll
      for (int nf = 0; nf < 4; ++nf)
        acc[m][nf] = __builtin_amdgcn_mfma_f32_16x16x32_bf16(afr[m], bfr[nf], acc[m][nf], 0, 0, 0);
  }

  float bias[4];
#pragma unroll
  for (int nf = 0; nf < 4; ++nf)
    bias[nf] = vok[nf] ? V2b[v0 + nf * 16 + lm] : 0.f;

  float* T = lt[wv];
  const int rq = lane >> 4, cq = lane & 15;
#pragma unroll
  for (int p = 0; p < 2; ++p) {
#pragma unroll
    for (int mm = 0; mm < 2; ++mm) {
      int m = p * 2 + mm;
#pragma unroll
      for (int nf = 0; nf < 4; ++nf)
#pragma unroll
        for (int r = 0; r < 4; ++r)
          T[(mm * 16 + lg * 4 + r) * 65 + nf * 16 + lm] = acc[m][nf][r] + bias[nf];
    }
#pragma unroll
    for (int it = 0; it < 8; ++it) {
      int trow = it * 4 + rq;
      f32x4 vv = *(const f32x4*)&T[trow * 65 + cq * 4];
      s16x4 hb;
      hb[0] = f2bf(vv[0]); hb[1] = f2bf(vv[1]); hb[2] = f2bf(vv[2]); hb[3] = f2bf(vv[3]);
      int orow = r0 + p * 32 + trow;
      unsigned short* dst = logit_row(outF, orow);
      *(s16x4*)&dst[v0 + cq * 4] = hb;
    }
  }
}

// ---------------------------------------------------------------------------
// K8: per-row softmax over bf16 logits (aligned region in d_out row slot),
// scale by p_gen, write f32 final_dist in place, zero 50 OOV cols,
// scatter-add attn_dist with WORKGROUP-scope atomics. One block per b.
// ---------------------------------------------------------------------------
#define K8_IT 30  // ceil(VOC_/1024)

__global__ __launch_bounds__(1024) void k8_final(
    const float* __restrict__ pgen, const int* __restrict__ code_ext,
    const float* __restrict__ attn, float* __restrict__ outF) {
  __shared__ float lm_[16], ls_[16];
  const int b = blockIdx.x, tid = threadIdx.x;
  float* row = outF + (size_t)b * VEXT_;
  const unsigned short* lrow = logit_row(outF, b);

  float lv[K8_IT];
#pragma unroll
  for (int i = 0; i < K8_IT; ++i) {
    int v = tid + i * 1024;
    lv[i] = (v < VOC_) ? bf2f(lrow[v]) : -3.4e38f;
  }
  float m = lv[0];
#pragma unroll
  for (int i = 1; i < K8_IT; ++i) m = fmaxf(m, lv[i]);
  for (int off = 32; off; off >>= 1) m = fmaxf(m, __shfl_xor(m, off));
  if ((tid & 63) == 0) lm_[tid >> 6] = m;
  __syncthreads();
  float M = lm_[0];
#pragma unroll
  for (int i = 1; i < 16; ++i) M = fmaxf(M, lm_[i]);
  float s = 0.f;
#pragma unroll
  for (int i = 0; i < K8_IT; ++i) {
    lv[i] = exp2f((lv[i] - M) * L2E);
    s += lv[i];
  }
  for (int off = 32; off; off >>= 1) s += __shfl_xor(s, off);
  if ((tid & 63) == 0) ls_[tid >> 6] = s;
  __syncthreads();
  float S = 0.f;
#pragma unroll
  for (int i = 0; i < 16; ++i) S += ls_[i];
  float pm = pgen[b] / S;
#pragma unroll
  for (int i = 0; i < K8_IT; ++i) {
    int v = tid + i * 1024;
    if (v < VOC_) row[v] = pm * lv[i];
  }
  if (tid < 50) row[VOC_ + tid] = 0.f;
  __syncthreads();  // drains vmcnt: all row stores are at the local L2
  if (tid < 512) {
    int idx = code_ext[b * 512 + tid];
    __hip_atomic_fetch_add(&row[idx], attn[b * 512 + tid],
                           __ATOMIC_RELAXED, __HIP_MEMORY_SCOPE_WORKGROUP);
  }
}

// ---------------------------------------------------------------------------
extern "C" void kernel_launch(void* const* d_in, const int* in_sizes, int n_in,
                              void* d_out, int out_size, void* d_ws, size_t ws_size,
                              hipStream_t stream) {
  (void)in_sizes; (void)n_in; (void)out_size;
  const float* h_i    = (const float*)d_in[0];
  const float* h_prev = (const float*)d_in[1];
  const float* c_prev = (const float*)d_in[2];
  const float* ctxp   = (const float*)d_in[3];
  const float* cov    = (const float*)d_in[4];
  const float* emb    = (const float*)d_in[5];
  const float* Wih    = (const float*)d_in[6];
  const float* Whh    = (const float*)d_in[7];
  const float* bih    = (const float*)d_in[8];
  const float* bhh    = (const float*)d_in[9];
  const float* W1w    = (const float*)d_in[10];
  const float* W1b    = (const float*)d_in[11];
  const float* W2w    = (const float*)d_in[12];
  const float* W2b    = (const float*)d_in[13];
  const float* V1w    = (const float*)d_in[14];
  const float* V1b    = (const float*)d_in[15];
  const float* V2w    = (const float*)d_in[16];
  const float* V2b    = (const float*)d_in[17];
  const float* Whw    = (const float*)d_in[18];
  const float* Wsw    = (const float*)d_in[19];
  const float* Wsb    = (const float*)d_in[20];
  const float* Wcw    = (const float*)d_in[21];
  const float* Vw     = (const float*)d_in[22];
  const int*   x      = (const int*)d_in[23];
  const int*   code   = (const int*)d_in[24];

  float* ws    = (float*)d_ws;
  float* x1    = ws;                 // 262144
  float* gates = ws + 262144;        // 262144
  float* decf  = ws + 524288;        // 65536
  // bw (bf16 Wh_w K=32 fragments, 16384 shorts) lives in the old e_t region
  // (ws+589824) -- e_t no longer exists; nothing else touches this region.
  unsigned short* bw = (unsigned short*)(ws + 589824);
  float* a_t   = ws + 851968;        // 262144
  unsigned short* pv1bf = (unsigned short*)(ws + 1114112);  // 196608 shorts
  float* pgen  = ws + 1212416;       // 512
  // v2bh: bf16 V2_w row-major [30080][384] = 11,550,720 shorts
  unsigned short* v2bh = (unsigned short*)(ws + 1212928);
  const size_t WS_NEEDED = (size_t)(1212928 + 5775360) * 4;  // 27,953,152 B
  const bool use_v6 = (ws_size >= WS_NEEDED);

  float* outF  = (float*)d_out;                    // final_dist 512 x 30051
  float* attn  = outF + (size_t)512 * VEXT_;       // 262144
  float* o_h   = attn + 262144;                    // 65536
  float* o_c   = o_h + 65536;                      // 65536
  float* o_cov = o_c + 65536;                      // 262144
  float* o_ctx = o_cov + 262144;                   // 65536

  k0_prep32<<<1, 256, 0, stream>>>(Whw, bw);
  if (use_v6) k0b_prepv2h<<<5640, 256, 0, stream>>>(V2w, v2bh);
  k1_x1<<<dim3(16, 16), 256, 0, stream>>>(emb, x, ctxp, W1w, W1b, x1);
  k2_gates<<<dim3(16, 16), 256, 0, stream>>>(x1, h_prev, Wih, Whh, bih, bhh, gates);
  k3_lstm<<<512, 128, 0, stream>>>(gates, c_prev, Wsw, Wsb, o_h, o_c, decf);
  k45_attn<<<512, 512, 0, stream>>>(h_i, bw, decf, cov, Wcw, Vw, a_t, o_cov, o_ctx);
  k6_pv1_pgen<<<512, 256, 0, stream>>>(o_h, o_c, o_ctx, emb, x, V1w, V1b, W2w, W2b,
                                       a_t, pv1bf, pgen, attn);
  if (use_v6)
    k7_vocab<<<940, 256, 0, stream>>>(pv1bf, v2bh, V2b, outF);
  else
    k7_vocab_fb<<<944, 256, 0, stream>>>(pv1bf, V2w, V2b, outF);
  k8_final<<<512, 1024, 0, stream>>>(pgen, code, attn, outF);
}